// Round 2
// baseline (1076.515 us; speedup 1.0000x reference)
//
#include <hip/hip_runtime.h>

#define NN 50000
#define NE 800000

typedef _Float16 f16;
typedef _Float16 f16x8 __attribute__((ext_vector_type(8)));
typedef float f32x4 __attribute__((ext_vector_type(4)));

__device__ __forceinline__ f16x8 fzero8() {
  f16x8 v;
#pragma unroll
  for (int i = 0; i < 8; ++i) v[i] = (f16)0.f;
  return v;
}

__device__ __forceinline__ f32x4 mfma16(f16x8 a, f16x8 b, f32x4 c) {
  return __builtin_amdgcn_mfma_f32_16x16x32_f16(a, b, c, 0, 0, 0);
}

// ---------------- prep kernels ----------------

__global__ void count_kernel(const int* __restrict__ dst, int* __restrict__ cnt) {
  int e = blockIdx.x * 256 + threadIdx.x;
  if (e < NE) atomicAdd(&cnt[dst[e]], 1);
}

// single-block exclusive scan over cnt -> off/cur, plus inv = 1/max(cnt,1)
__global__ void scan_kernel(const int* __restrict__ cnt, int* __restrict__ off,
                            int* __restrict__ cur, float* __restrict__ inv) {
  __shared__ int part[1024];
  const int t = threadIdx.x;
  const int CH = (NN + 1023) / 1024;
  const int i0 = t * CH, i1 = (i0 + CH < NN) ? i0 + CH : NN;
  int s = 0;
  for (int i = i0; i < i1; ++i) s += cnt[i];
  part[t] = s;
  __syncthreads();
  for (int d = 1; d < 1024; d <<= 1) {
    int v = (t >= d) ? part[t - d] : 0;
    __syncthreads();
    part[t] += v;
    __syncthreads();
  }
  int base = (t > 0) ? part[t - 1] : 0;
  for (int i = i0; i < i1; ++i) {
    off[i] = base;
    cur[i] = base;
    inv[i] = 1.0f / fmaxf((float)cnt[i], 1.0f);
    base += cnt[i];
  }
  if (t == 1023) off[NN] = NE;
}

// scatter edges into dst-sorted order; also build packed encoder rows
// [x_src(5) | x_dst(5) | ea(4) | 0 0] f16[16] at the permuted position.
__global__ void scatter_pack(const float* __restrict__ x, const float* __restrict__ ea,
                             const int* __restrict__ src, const int* __restrict__ dst,
                             int* __restrict__ cur, int* __restrict__ psrc,
                             int* __restrict__ pdst, f16* __restrict__ A) {
  int e = blockIdx.x * 256 + threadIdx.x;
  if (e >= NE) return;
  int s = src[e], d = dst[e];
  int pos = atomicAdd(&cur[d], 1);
  psrc[pos] = s;
  pdst[pos] = d;
  f16 row[16];
#pragma unroll
  for (int i = 0; i < 5; ++i) { row[i] = (f16)x[s * 5 + i]; row[5 + i] = (f16)x[d * 5 + i]; }
#pragma unroll
  for (int i = 0; i < 4; ++i) row[10 + i] = (f16)ea[e * 4 + i];
  row[14] = (f16)0.f; row[15] = (f16)0.f;
  *(f16x8*)(A + (size_t)pos * 16) = *(f16x8*)row;
  *(f16x8*)(A + (size_t)pos * 16 + 8) = *(f16x8*)(row + 8);
}

// W is [K_src][Nw] row-major f32; writes out[n*Kd + kd + kk] = W[(ks+kk)*Nw + n]
__global__ void prep_w(const float* __restrict__ W, int Nw, f16* __restrict__ out,
                       int Kd, int ks, int kd, int klen, int nc) {
  int idx = blockIdx.x * 256 + threadIdx.x;
  if (idx >= klen * nc) return;
  int kk = idx / nc, n = idx % nc;
  out[n * Kd + kd + kk] = (f16)W[(ks + kk) * Nw + n];
}

// segmented mean over dst-sorted edge latents: one wave per node, lane = col
__global__ void agg_kernel(const f16* __restrict__ e, const int* __restrict__ off,
                           const float* __restrict__ inv, f16* __restrict__ aggh) {
  const int n = blockIdx.x * 4 + (threadIdx.x >> 6);
  if (n >= NN) return;
  const int lane = threadIdx.x & 63;
  const int o0 = off[n], o1 = off[n + 1];
  float a = 0.f, b = 0.f;
  int i = o0;
  for (; i + 2 <= o1; i += 2) {
    a += (float)e[(size_t)i * 64 + lane];
    b += (float)e[(size_t)(i + 1) * 64 + lane];
  }
  if (i < o1) a += (float)e[(size_t)i * 64 + lane];
  aggh[(size_t)n * 64 + lane] = (f16)((a + b) * inv[n]);
}

// ---------------- edge MLP ----------------
// STAGE: 0=encoder (A from packed Aenc, write el)
//        1=processor (A=[xh[src]|xh[dst]|el], write ed and el += ed)
//        2=decoder   (A same as proc, write ed only)
// No atomics; aggregation is a separate segmented pass.
template <int STAGE, int KT1>
__global__ void edge_mlp_kernel(const f16* __restrict__ Aenc,
                                const f16* __restrict__ xh,
                                const f16* elr, f16* elw, f16* edw,
                                const int* __restrict__ psrc,
                                const int* __restrict__ pdst,
                                const f16* __restrict__ B1,
                                const f16* __restrict__ B2,
                                const float* __restrict__ b1,
                                const float* __restrict__ b2) {
  constexpr int K1 = KT1 * 32;
  __shared__ __align__(16) f16 h1s[4][16][72];
  const int wave = threadIdx.x >> 6;
  const int lane = threadIdx.x & 63;
  const int l15 = lane & 15, lg = lane >> 4;
  const int nwaves = gridDim.x * 4;
  const int wid = blockIdx.x * 4 + wave;
  const int NG = NE / 16;

  f16x8 B1f[KT1][4];
#pragma unroll
  for (int kk = 0; kk < KT1; ++kk)
#pragma unroll
    for (int nt = 0; nt < 4; ++nt)
      B1f[kk][nt] = *(const f16x8*)(B1 + (nt * 16 + l15) * K1 + kk * 32 + lg * 8);
  f16x8 B2f[2][4];
#pragma unroll
  for (int kk = 0; kk < 2; ++kk)
#pragma unroll
    for (int nt = 0; nt < 4; ++nt)
      B2f[kk][nt] = *(const f16x8*)(B2 + (nt * 16 + l15) * 64 + kk * 32 + lg * 8);
  float bias1[4], bias2[4];
#pragma unroll
  for (int nt = 0; nt < 4; ++nt) { bias1[nt] = b1[nt * 16 + l15]; bias2[nt] = b2[nt * 16 + l15]; }

  for (int g = wid; g < NG; g += nwaves) {
    const int e0 = g * 16;
    const int erA = e0 + l15;

    f32x4 acc[4];
#pragma unroll
    for (int nt = 0; nt < 4; ++nt) { acc[nt][0] = 0.f; acc[nt][1] = 0.f; acc[nt][2] = 0.f; acc[nt][3] = 0.f; }

    if (STAGE == 0) {
      f16x8 a = fzero8();
      if (lg < 2) a = *(const f16x8*)(Aenc + (size_t)erA * 16 + lg * 8);
#pragma unroll
      for (int nt = 0; nt < 4; ++nt) acc[nt] = mfma16(a, B1f[0][nt], acc[nt]);
    } else {
      const int s = psrc[erA];
      const int d = pdst[erA];
#pragma unroll
      for (int kk = 0; kk < KT1; ++kk) {
        const f16* base = (kk < 2) ? (xh + (size_t)s * 64 + kk * 32)
                        : (kk < 4) ? (xh + (size_t)d * 64 + (kk - 2) * 32)
                                   : (elr + (size_t)erA * 64 + (kk - 4) * 32);
        f16x8 a = *(const f16x8*)(base + lg * 8);
#pragma unroll
        for (int nt = 0; nt < 4; ++nt) acc[nt] = mfma16(a, B1f[kk][nt], acc[nt]);
      }
    }
    // bias + relu, stage h1 to LDS (C-layout -> A-layout); per-wave slice, no barrier
#pragma unroll
    for (int nt = 0; nt < 4; ++nt)
#pragma unroll
      for (int r = 0; r < 4; ++r) {
        float h = fmaxf(acc[nt][r] + bias1[nt], 0.f);
        h1s[wave][lg * 4 + r][nt * 16 + l15] = (f16)h;
      }

    f32x4 out[4];
#pragma unroll
    for (int nt = 0; nt < 4; ++nt) { out[nt][0] = 0.f; out[nt][1] = 0.f; out[nt][2] = 0.f; out[nt][3] = 0.f; }
#pragma unroll
    for (int kk = 0; kk < 2; ++kk) {
      f16x8 hf = *(const f16x8*)&h1s[wave][l15][kk * 32 + lg * 8];
#pragma unroll
      for (int nt = 0; nt < 4; ++nt) out[nt] = mfma16(hf, B2f[kk][nt], out[nt]);
    }

    // stage output (bias added) back to LDS rows, then vector stores
#pragma unroll
    for (int nt = 0; nt < 4; ++nt)
#pragma unroll
      for (int r = 0; r < 4; ++r)
        h1s[wave][lg * 4 + r][nt * 16 + l15] = (f16)(out[nt][r] + bias2[nt]);

    const size_t rowb = (size_t)(e0 + l15) * 64 + lg * 16;
    f16x8 v0 = *(const f16x8*)&h1s[wave][l15][lg * 16];
    f16x8 v1 = *(const f16x8*)&h1s[wave][l15][lg * 16 + 8];
    if (STAGE == 0) {
      *(f16x8*)(elw + rowb) = v0;
      *(f16x8*)(elw + rowb + 8) = v1;
    } else if (STAGE == 1) {
      *(f16x8*)(edw + rowb) = v0;
      *(f16x8*)(edw + rowb + 8) = v1;
      f16x8 o0 = *(const f16x8*)(elr + rowb);
      f16x8 o1 = *(const f16x8*)(elr + rowb + 8);
      f16x8 n0, n1;
#pragma unroll
      for (int j = 0; j < 8; ++j) {
        n0[j] = (f16)((float)o0[j] + (float)v0[j]);
        n1[j] = (f16)((float)o1[j] + (float)v1[j]);
      }
      *(f16x8*)(elw + rowb) = n0;
      *(f16x8*)(elw + rowb + 8) = n1;
    } else {
      *(f16x8*)(edw + rowb) = v0;
      *(f16x8*)(edw + rowb + 8) = v1;
    }
  }
}

// ---------------- node MLP ----------------
// STAGE: 0=encoder (A=[x_raw(5,pad32)|aggh], out: xl=v, xh=f16(v))
//        1=processor (A=[xh|aggh], xl += v, xh mirror)
//        2=decoder   (A=[xh|aggh], write d_out[N][7])
template <int STAGE, int KT1, int NT2, int OUTW>
__global__ void node_mlp_kernel(const float* __restrict__ xraw,
                                const f16* xh,
                                const f16* __restrict__ aggh,
                                const f16* __restrict__ B1,
                                const f16* __restrict__ B2,
                                const float* __restrict__ b1,
                                const float* __restrict__ b2,
                                float* __restrict__ xl,
                                f16* xho,
                                float* __restrict__ outp) {
  constexpr int K1 = KT1 * 32;
  __shared__ __align__(16) f16 h1s[4][16][72];
  const int wave = threadIdx.x >> 6;
  const int lane = threadIdx.x & 63;
  const int l15 = lane & 15, lg = lane >> 4;
  const int nwaves = gridDim.x * 4;
  const int wid = blockIdx.x * 4 + wave;
  const int NG = NN / 16;

  f16x8 B1f[KT1][4];
#pragma unroll
  for (int kk = 0; kk < KT1; ++kk)
#pragma unroll
    for (int nt = 0; nt < 4; ++nt)
      B1f[kk][nt] = *(const f16x8*)(B1 + (nt * 16 + l15) * K1 + kk * 32 + lg * 8);
  f16x8 B2f[2][NT2];
#pragma unroll
  for (int kk = 0; kk < 2; ++kk)
#pragma unroll
    for (int nt = 0; nt < NT2; ++nt)
      B2f[kk][nt] = *(const f16x8*)(B2 + (nt * 16 + l15) * 64 + kk * 32 + lg * 8);
  float bias1[4], bias2[NT2];
#pragma unroll
  for (int nt = 0; nt < 4; ++nt) bias1[nt] = b1[nt * 16 + l15];
#pragma unroll
  for (int nt = 0; nt < NT2; ++nt) bias2[nt] = (nt * 16 + l15 < OUTW) ? b2[nt * 16 + l15] : 0.f;

  for (int g = wid; g < NG; g += nwaves) {
    const int n0 = g * 16;
    const int rA = n0 + l15;

    f32x4 acc[4];
#pragma unroll
    for (int nt = 0; nt < 4; ++nt) { acc[nt][0] = 0.f; acc[nt][1] = 0.f; acc[nt][2] = 0.f; acc[nt][3] = 0.f; }

#pragma unroll
    for (int kk = 0; kk < KT1; ++kk) {
      f16x8 a;
      if (STAGE == 0) {
        if (kk == 0) {
          a = fzero8();
          if (lg == 0) {
#pragma unroll
            for (int j = 0; j < 5; ++j) a[j] = (f16)xraw[(size_t)rA * 5 + j];
          }
        } else {
          a = *(const f16x8*)(aggh + (size_t)rA * 64 + (kk - 1) * 32 + lg * 8);
        }
      } else {
        a = (kk < 2) ? *(const f16x8*)(xh + (size_t)rA * 64 + kk * 32 + lg * 8)
                     : *(const f16x8*)(aggh + (size_t)rA * 64 + (kk - 2) * 32 + lg * 8);
      }
#pragma unroll
      for (int nt = 0; nt < 4; ++nt) acc[nt] = mfma16(a, B1f[kk][nt], acc[nt]);
    }
#pragma unroll
    for (int nt = 0; nt < 4; ++nt)
#pragma unroll
      for (int r = 0; r < 4; ++r) {
        float h = fmaxf(acc[nt][r] + bias1[nt], 0.f);
        h1s[wave][lg * 4 + r][nt * 16 + l15] = (f16)h;
      }

    f32x4 out[NT2];
#pragma unroll
    for (int nt = 0; nt < NT2; ++nt) { out[nt][0] = 0.f; out[nt][1] = 0.f; out[nt][2] = 0.f; out[nt][3] = 0.f; }
#pragma unroll
    for (int kk = 0; kk < 2; ++kk) {
      f16x8 hf = *(const f16x8*)&h1s[wave][l15][kk * 32 + lg * 8];
#pragma unroll
      for (int nt = 0; nt < NT2; ++nt) out[nt] = mfma16(hf, B2f[kk][nt], out[nt]);
    }
#pragma unroll
    for (int r = 0; r < 4; ++r) {
      const int row = n0 + lg * 4 + r;
#pragma unroll
      for (int nt = 0; nt < NT2; ++nt) {
        const int col = nt * 16 + l15;
        float v = out[nt][r] + bias2[nt];
        if (STAGE == 0) {
          xl[(size_t)row * 64 + col] = v;
          xho[(size_t)row * 64 + col] = (f16)v;
        } else if (STAGE == 1) {
          float nv = xl[(size_t)row * 64 + col] + v;
          xl[(size_t)row * 64 + col] = nv;
          xho[(size_t)row * 64 + col] = (f16)nv;
        } else {
          if (col < OUTW) outp[(size_t)row * OUTW + col] = v;
        }
      }
    }
  }
}

// ---------------- launch ----------------

extern "C" void kernel_launch(void* const* d_in, const int* in_sizes, int n_in,
                              void* d_out, int out_size, void* d_ws, size_t ws_size,
                              hipStream_t stream) {
  const float* x  = (const float*)d_in[0];
  const int* ei   = (const int*)d_in[1];
  const float* ea = (const float*)d_in[2];
  const float* enc_e_w1 = (const float*)d_in[3];  const float* enc_e_b1 = (const float*)d_in[4];
  const float* enc_e_w2 = (const float*)d_in[5];  const float* enc_e_b2 = (const float*)d_in[6];
  const float* enc_n_w1 = (const float*)d_in[7];  const float* enc_n_b1 = (const float*)d_in[8];
  const float* enc_n_w2 = (const float*)d_in[9];  const float* enc_n_b2 = (const float*)d_in[10];
  const float* proc_e_w1 = (const float*)d_in[11]; const float* proc_e_b1 = (const float*)d_in[12];
  const float* proc_e_w2 = (const float*)d_in[13]; const float* proc_e_b2 = (const float*)d_in[14];
  const float* proc_n_w1 = (const float*)d_in[15]; const float* proc_n_b1 = (const float*)d_in[16];
  const float* proc_n_w2 = (const float*)d_in[17]; const float* proc_n_b2 = (const float*)d_in[18];
  const float* dec_e_w1 = (const float*)d_in[19]; const float* dec_e_b1 = (const float*)d_in[20];
  const float* dec_e_w2 = (const float*)d_in[21]; const float* dec_e_b2 = (const float*)d_in[22];
  const float* dec_n_w1 = (const float*)d_in[23]; const float* dec_n_b1 = (const float*)d_in[24];
  const float* dec_n_w2 = (const float*)d_in[25]; const float* dec_n_b2 = (const float*)d_in[26];

  const int* src = ei;
  const int* dst = ei + NE;

  char* p = (char*)d_ws;
  f16* el    = (f16*)p;   p += (size_t)NE * 64 * 2;
  f16* ed    = (f16*)p;   p += (size_t)NE * 64 * 2;
  f16* Aenc  = (f16*)p;   p += (size_t)NE * 16 * 2;
  float* xl  = (float*)p; p += (size_t)NN * 64 * 4;
  f16* xh    = (f16*)p;   p += (size_t)NN * 64 * 2;
  f16* aggh  = (f16*)p;   p += (size_t)NN * 64 * 2;
  int* cnt   = (int*)p;   p += (size_t)NN * 4;
  int* off   = (int*)p;   p += (size_t)(NN + 1) * 4;
  int* cur   = (int*)p;   p += (size_t)NN * 4;
  float* inv = (float*)p; p += (size_t)NN * 4;
  int* psrc  = (int*)p;   p += (size_t)NE * 4;
  int* pdst  = (int*)p;   p += (size_t)NE * 4;
  f16* wb    = (f16*)p;
  f16* W1T_ence = wb; wb += 64 * 32;
  f16* W2T_ence = wb; wb += 64 * 64;
  f16* W1T_encn = wb; wb += 64 * 96;
  f16* W2T_encn = wb; wb += 64 * 64;
  f16* W1T_proce = wb; wb += 64 * 192;
  f16* W2T_proce = wb; wb += 64 * 64;
  f16* W1T_procn = wb; wb += 64 * 128;
  f16* W2T_procn = wb; wb += 64 * 64;
  f16* W1T_dece = wb; wb += 64 * 192;
  f16* W2T_dece = wb; wb += 64 * 64;
  f16* W1T_decn = wb; wb += 64 * 128;
  f16* W2T_decn = wb; wb += 16 * 64;
  const size_t wbytes = (size_t)((char*)wb - p);

  hipMemsetAsync(cnt, 0, (size_t)NN * 4, stream);
  hipMemsetAsync((void*)W1T_ence, 0, wbytes, stream);

  count_kernel<<<(NE + 255) / 256, 256, 0, stream>>>(dst, cnt);
  scan_kernel<<<1, 1024, 0, stream>>>(cnt, off, cur, inv);
  scatter_pack<<<(NE + 255) / 256, 256, 0, stream>>>(x, ea, src, dst, cur, psrc, pdst, Aenc);

  auto PREP = [&](const float* W, int Nw, f16* outw, int Kd, int ks, int kd, int klen, int nc) {
    int tot = klen * nc;
    prep_w<<<(tot + 255) / 256, 256, 0, stream>>>(W, Nw, outw, Kd, ks, kd, klen, nc);
  };
  PREP(enc_e_w1, 64, W1T_ence, 32, 0, 0, 14, 64);
  PREP(enc_e_w2, 64, W2T_ence, 64, 0, 0, 64, 64);
  PREP(enc_n_w1, 64, W1T_encn, 96, 0, 0, 5, 64);
  PREP(enc_n_w1, 64, W1T_encn, 96, 5, 32, 64, 64);
  PREP(enc_n_w2, 64, W2T_encn, 64, 0, 0, 64, 64);
  PREP(proc_e_w1, 64, W1T_proce, 192, 0, 0, 192, 64);
  PREP(proc_e_w2, 64, W2T_proce, 64, 0, 0, 64, 64);
  PREP(proc_n_w1, 64, W1T_procn, 128, 0, 0, 128, 64);
  PREP(proc_n_w2, 64, W2T_procn, 64, 0, 0, 64, 64);
  PREP(dec_e_w1, 64, W1T_dece, 192, 0, 0, 192, 64);
  PREP(dec_e_w2, 64, W2T_dece, 64, 0, 0, 64, 64);
  PREP(dec_n_w1, 64, W1T_decn, 128, 0, 0, 128, 64);
  PREP(dec_n_w2, 7, W2T_decn, 64, 0, 0, 64, 7);

  // ---- encoder ----
  edge_mlp_kernel<0, 1><<<1024, 256, 0, stream>>>(Aenc, xh, el, el, ed, psrc, pdst,
                                                  W1T_ence, W2T_ence, enc_e_b1, enc_e_b2);
  agg_kernel<<<(NN + 3) / 4, 256, 0, stream>>>(el, off, inv, aggh);
  node_mlp_kernel<0, 3, 4, 64><<<256, 256, 0, stream>>>(x, xh, aggh, W1T_encn, W2T_encn,
                                                        enc_n_b1, enc_n_b2, xl, xh, (float*)d_out);
  // ---- 2 processor rounds (shared weights, residuals) ----
  for (int r = 0; r < 2; ++r) {
    edge_mlp_kernel<1, 6><<<2048, 256, 0, stream>>>(Aenc, xh, el, el, ed, psrc, pdst,
                                                    W1T_proce, W2T_proce, proc_e_b1, proc_e_b2);
    agg_kernel<<<(NN + 3) / 4, 256, 0, stream>>>(ed, off, inv, aggh);
    node_mlp_kernel<1, 4, 4, 64><<<256, 256, 0, stream>>>(x, xh, aggh, W1T_procn, W2T_procn,
                                                          proc_n_b1, proc_n_b2, xl, xh, (float*)d_out);
  }
  // ---- decoder ----
  edge_mlp_kernel<2, 6><<<2048, 256, 0, stream>>>(Aenc, xh, el, el, ed, psrc, pdst,
                                                  W1T_dece, W2T_dece, dec_e_b1, dec_e_b2);
  agg_kernel<<<(NN + 3) / 4, 256, 0, stream>>>(ed, off, inv, aggh);
  node_mlp_kernel<2, 4, 1, 7><<<256, 256, 0, stream>>>(x, xh, aggh, W1T_decn, W2T_decn,
                                                       dec_n_b1, dec_n_b2, xl, xh, (float*)d_out);
}

// Round 4
// 1062.255 us; speedup vs baseline: 1.0134x; 1.0134x over previous
//
#include <hip/hip_runtime.h>

#define NN 50000
#define NE 800000

typedef _Float16 f16;
typedef _Float16 f16x8 __attribute__((ext_vector_type(8)));
typedef _Float16 f16x4 __attribute__((ext_vector_type(4)));
typedef float f32x4 __attribute__((ext_vector_type(4)));

__device__ __forceinline__ f16x8 fzero8() {
  f16x8 v;
#pragma unroll
  for (int i = 0; i < 8; ++i) v[i] = (f16)0.f;
  return v;
}

__device__ __forceinline__ f32x4 mfma16(f16x8 a, f16x8 b, f32x4 c) {
  return __builtin_amdgcn_mfma_f32_16x16x32_f16(a, b, c, 0, 0, 0);
}

// ---------------- prep kernels ----------------

__global__ void count_kernel(const int* __restrict__ dst, int* __restrict__ cnt) {
  int e = blockIdx.x * 256 + threadIdx.x;
  if (e < NE) atomicAdd(&cnt[dst[e]], 1);
}

// single-block exclusive scan over cnt -> off/cur, plus inv = 1/max(cnt,1)
__global__ void scan_kernel(const int* __restrict__ cnt, int* __restrict__ off,
                            int* __restrict__ cur, float* __restrict__ inv) {
  __shared__ int part[1024];
  const int t = threadIdx.x;
  const int CH = (NN + 1023) / 1024;
  const int i0 = t * CH, i1 = (i0 + CH < NN) ? i0 + CH : NN;
  int s = 0;
  for (int i = i0; i < i1; ++i) s += cnt[i];
  part[t] = s;
  __syncthreads();
  for (int d = 1; d < 1024; d <<= 1) {
    int v = (t >= d) ? part[t - d] : 0;
    __syncthreads();
    part[t] += v;
    __syncthreads();
  }
  int base = (t > 0) ? part[t - 1] : 0;
  for (int i = i0; i < i1; ++i) {
    off[i] = base;
    cur[i] = base;
    inv[i] = 1.0f / fmaxf((float)cnt[i], 1.0f);
    base += cnt[i];
  }
  if (t == 1023) off[NN] = NE;
}

// scatter edges into dst-sorted order; also build packed encoder rows
// [x_src(5) | x_dst(5) | ea(4) | 0 0] f16[16] at the permuted position.
__global__ void scatter_pack(const float* __restrict__ x, const float* __restrict__ ea,
                             const int* __restrict__ src, const int* __restrict__ dst,
                             int* __restrict__ cur, int* __restrict__ psrc,
                             int* __restrict__ pdst, f16* __restrict__ A) {
  int e = blockIdx.x * 256 + threadIdx.x;
  if (e >= NE) return;
  int s = src[e], d = dst[e];
  int pos = atomicAdd(&cur[d], 1);
  psrc[pos] = s;
  pdst[pos] = d;
  f16 row[16];
#pragma unroll
  for (int i = 0; i < 5; ++i) { row[i] = (f16)x[s * 5 + i]; row[5 + i] = (f16)x[d * 5 + i]; }
#pragma unroll
  for (int i = 0; i < 4; ++i) row[10 + i] = (f16)ea[e * 4 + i];
  row[14] = (f16)0.f; row[15] = (f16)0.f;
  __builtin_nontemporal_store(*(f16x8*)row, (f16x8*)(A + (size_t)pos * 16));
  __builtin_nontemporal_store(*(f16x8*)(row + 8), (f16x8*)(A + (size_t)pos * 16 + 8));
}

// all 13 weight transposes in one launch; block b handles matrix b
struct PrepPtrs { const float* W[13]; };
__global__ void prep_all(PrepPtrs P, f16* __restrict__ out) {
  const int Nw[13]   = {64,64,64,64,64,64,64,64,64,64,64,64,7};
  const int Kd[13]   = {32,64,96,96,64,192,64,128,64,192,64,128,64};
  const int ks[13]   = {0,0,0,5,0,0,0,0,0,0,0,0,0};
  const int kd[13]   = {0,0,0,32,0,0,0,0,0,0,0,0,0};
  const int klen[13] = {14,64,5,64,64,192,64,128,64,192,64,128,64};
  const int nc[13]   = {64,64,64,64,64,64,64,64,64,64,64,64,7};
  const int ofs[13]  = {0,2048,6144,6144,12288,16384,28672,32768,40960,45056,57344,61440,69632};
  const int m = blockIdx.x;
  const float* W = P.W[m];
  const int tot = klen[m] * nc[m];
  for (int idx = threadIdx.x; idx < tot; idx += 256) {
    int kk = idx / nc[m], n = idx % nc[m];
    out[ofs[m] + n * Kd[m] + kd[m] + kk] = (f16)W[(ks[m] + kk) * Nw[m] + n];
  }
}

// ---------------- segmented mean ----------------
// one wave per node; 4 edges/iter, 4 cols per lane, shfl reduce.
// STAGE 0: aggh = mean,      M = mean   (encoder)
// STAGE 1: aggh = mean - M,  M = mean   (processor rounds)
// STAGE 2: aggh = mean - M,  M untouched (decoder)
template <int STAGE>
__global__ void agg_kernel(const f16* __restrict__ e, const int* __restrict__ off,
                           const float* __restrict__ inv, float* __restrict__ M,
                           f16* __restrict__ aggh) {
  const int n = blockIdx.x * 4 + (threadIdx.x >> 6);
  if (n >= NN) return;
  const int lane = threadIdx.x & 63;
  const int eo = lane >> 4;   // edge-in-quad 0..3
  const int cp = lane & 15;   // col group: cols cp*4..cp*4+3
  const int o0 = off[n], o1 = off[n + 1];
  float s0 = 0.f, s1 = 0.f, s2 = 0.f, s3 = 0.f;
  for (int i = o0 + eo; i < o1; i += 4) {
    f16x4 v = __builtin_nontemporal_load((const f16x4*)(e + (size_t)i * 64 + cp * 4));
    s0 += (float)v[0]; s1 += (float)v[1]; s2 += (float)v[2]; s3 += (float)v[3];
  }
  s0 += __shfl_xor(s0, 16); s0 += __shfl_xor(s0, 32);
  s1 += __shfl_xor(s1, 16); s1 += __shfl_xor(s1, 32);
  s2 += __shfl_xor(s2, 16); s2 += __shfl_xor(s2, 32);
  s3 += __shfl_xor(s3, 16); s3 += __shfl_xor(s3, 32);
  if (eo == 0) {
    const float iv = inv[n];
    float m0 = s0 * iv, m1 = s1 * iv, m2 = s2 * iv, m3 = s3 * iv;
    float a0 = m0, a1 = m1, a2 = m2, a3 = m3;
    if (STAGE != 0) {
      f32x4 prev = *(const f32x4*)(M + (size_t)n * 64 + cp * 4);
      a0 = m0 - prev[0]; a1 = m1 - prev[1]; a2 = m2 - prev[2]; a3 = m3 - prev[3];
    }
    if (STAGE != 2) {
      f32x4 mm; mm[0] = m0; mm[1] = m1; mm[2] = m2; mm[3] = m3;
      *(f32x4*)(M + (size_t)n * 64 + cp * 4) = mm;
    }
    f16x4 o; o[0] = (f16)a0; o[1] = (f16)a1; o[2] = (f16)a2; o[3] = (f16)a3;
    *(f16x4*)(aggh + (size_t)n * 64 + cp * 4) = o;
  }
}

// ---------------- edge MLP ----------------
// STAGE: 0=encoder (A from packed Aenc, write el)
//        1=processor/decoder (A=[xh[src]|xh[dst]|el], el += ed in place)
template <int STAGE, int KT1>
__global__ void edge_mlp_kernel(const f16* __restrict__ Aenc,
                                const f16* __restrict__ xh,
                                const f16* elr, f16* eout,
                                const int* __restrict__ psrc,
                                const int* __restrict__ pdst,
                                const f16* __restrict__ B1,
                                const f16* __restrict__ B2,
                                const float* __restrict__ b1,
                                const float* __restrict__ b2) {
  constexpr int K1 = KT1 * 32;
  __shared__ __align__(16) f16 h1s[4][16][72];
  const int wave = threadIdx.x >> 6;
  const int lane = threadIdx.x & 63;
  const int l15 = lane & 15, lg = lane >> 4;
  const int nwaves = gridDim.x * 4;
  const int wid = blockIdx.x * 4 + wave;
  const int NG = NE / 16;

  f16x8 B1f[KT1][4];
#pragma unroll
  for (int kk = 0; kk < KT1; ++kk)
#pragma unroll
    for (int nt = 0; nt < 4; ++nt)
      B1f[kk][nt] = *(const f16x8*)(B1 + (nt * 16 + l15) * K1 + kk * 32 + lg * 8);
  f16x8 B2f[2][4];
#pragma unroll
  for (int kk = 0; kk < 2; ++kk)
#pragma unroll
    for (int nt = 0; nt < 4; ++nt)
      B2f[kk][nt] = *(const f16x8*)(B2 + (nt * 16 + l15) * 64 + kk * 32 + lg * 8);
  float bias1[4], bias2[4];
#pragma unroll
  for (int nt = 0; nt < 4; ++nt) { bias1[nt] = b1[nt * 16 + l15]; bias2[nt] = b2[nt * 16 + l15]; }

  // index prefetch pipeline
  int sCur = 0, dCur = 0;
  if (STAGE != 0 && wid < NG) {
    sCur = psrc[wid * 16 + l15];
    dCur = pdst[wid * 16 + l15];
  }

  for (int g = wid; g < NG; g += nwaves) {
    const int e0 = g * 16;
    const int erA = e0 + l15;

    int s = sCur, d = dCur;
    if (STAGE != 0) {
      const int gN = g + nwaves;
      if (gN < NG) { sCur = psrc[gN * 16 + l15]; dCur = pdst[gN * 16 + l15]; }
    }

    f32x4 acc[4];
#pragma unroll
    for (int nt = 0; nt < 4; ++nt) { acc[nt][0] = 0.f; acc[nt][1] = 0.f; acc[nt][2] = 0.f; acc[nt][3] = 0.f; }

    f16x8 o0 = fzero8(), o1 = fzero8();  // el fragment kept for residual
    if (STAGE == 0) {
      f16x8 a = fzero8();
      if (lg < 2) a = __builtin_nontemporal_load((const f16x8*)(Aenc + (size_t)erA * 16 + lg * 8));
#pragma unroll
      for (int nt = 0; nt < 4; ++nt) acc[nt] = mfma16(a, B1f[0][nt], acc[nt]);
    } else {
#pragma unroll
      for (int kk = 0; kk < KT1; ++kk) {
        f16x8 a;
        if (kk < 2) {
          a = *(const f16x8*)(xh + (size_t)s * 64 + kk * 32 + lg * 8);
        } else if (kk < 4) {
          a = *(const f16x8*)(xh + (size_t)d * 64 + (kk - 2) * 32 + lg * 8);
        } else {
          a = __builtin_nontemporal_load((const f16x8*)(elr + (size_t)erA * 64 + (kk - 4) * 32 + lg * 8));
          if (kk == 4) o0 = a; else o1 = a;
        }
#pragma unroll
        for (int nt = 0; nt < 4; ++nt) acc[nt] = mfma16(a, B1f[kk][nt], acc[nt]);
      }
    }
    // bias + relu, stage h1 to LDS (C-layout -> A-layout); per-wave slice, no barrier
#pragma unroll
    for (int nt = 0; nt < 4; ++nt)
#pragma unroll
      for (int r = 0; r < 4; ++r) {
        float h = fmaxf(acc[nt][r] + bias1[nt], 0.f);
        h1s[wave][lg * 4 + r][nt * 16 + l15] = (f16)h;
      }

    f32x4 out[4];
#pragma unroll
    for (int nt = 0; nt < 4; ++nt) { out[nt][0] = 0.f; out[nt][1] = 0.f; out[nt][2] = 0.f; out[nt][3] = 0.f; }
#pragma unroll
    for (int kk = 0; kk < 2; ++kk) {
      f16x8 hf = *(const f16x8*)&h1s[wave][l15][kk * 32 + lg * 8];
#pragma unroll
      for (int nt = 0; nt < 4; ++nt) out[nt] = mfma16(hf, B2f[kk][nt], out[nt]);
    }

    // stage output (bias added) back to LDS rows
#pragma unroll
    for (int nt = 0; nt < 4; ++nt)
#pragma unroll
      for (int r = 0; r < 4; ++r)
        h1s[wave][lg * 4 + r][nt * 16 + l15] = (f16)(out[nt][r] + bias2[nt]);

    // epilogue at 8-col granularity so residual can use in-register o0/o1
    f16x8 v0 = *(const f16x8*)&h1s[wave][l15][lg * 8];
    f16x8 v1 = *(const f16x8*)&h1s[wave][l15][32 + lg * 8];
    f16* p0 = eout + (size_t)erA * 64 + lg * 8;
    if (STAGE == 1) {
      f16x8 n0, n1;
#pragma unroll
      for (int j = 0; j < 8; ++j) {
        n0[j] = (f16)((float)o0[j] + (float)v0[j]);
        n1[j] = (f16)((float)o1[j] + (float)v1[j]);
      }
      __builtin_nontemporal_store(n0, (f16x8*)p0);
      __builtin_nontemporal_store(n1, (f16x8*)(p0 + 32));
    } else {
      __builtin_nontemporal_store(v0, (f16x8*)p0);
      __builtin_nontemporal_store(v1, (f16x8*)(p0 + 32));
    }
  }
}

// ---------------- node MLP ----------------
// STAGE: 0=encoder (A=[x_raw(5,pad32)|aggh], out: xl=v, xh=f16(v))
//        1=processor (A=[xh|aggh], xl += v, xh mirror)
//        2=decoder   (A=[xh|aggh], write d_out[N][7])
template <int STAGE, int KT1, int NT2, int OUTW>
__global__ void node_mlp_kernel(const float* __restrict__ xraw,
                                const f16* xh,
                                const f16* __restrict__ aggh,
                                const f16* __restrict__ B1,
                                const f16* __restrict__ B2,
                                const float* __restrict__ b1,
                                const float* __restrict__ b2,
                                float* __restrict__ xl,
                                f16* xho,
                                float* __restrict__ outp) {
  constexpr int K1 = KT1 * 32;
  __shared__ __align__(16) f16 h1s[4][16][72];
  const int wave = threadIdx.x >> 6;
  const int lane = threadIdx.x & 63;
  const int l15 = lane & 15, lg = lane >> 4;
  const int nwaves = gridDim.x * 4;
  const int wid = blockIdx.x * 4 + wave;
  const int NG = NN / 16;

  f16x8 B1f[KT1][4];
#pragma unroll
  for (int kk = 0; kk < KT1; ++kk)
#pragma unroll
    for (int nt = 0; nt < 4; ++nt)
      B1f[kk][nt] = *(const f16x8*)(B1 + (nt * 16 + l15) * K1 + kk * 32 + lg * 8);
  f16x8 B2f[2][NT2];
#pragma unroll
  for (int kk = 0; kk < 2; ++kk)
#pragma unroll
    for (int nt = 0; nt < NT2; ++nt)
      B2f[kk][nt] = *(const f16x8*)(B2 + (nt * 16 + l15) * 64 + kk * 32 + lg * 8);
  float bias1[4], bias2[NT2];
#pragma unroll
  for (int nt = 0; nt < 4; ++nt) bias1[nt] = b1[nt * 16 + l15];
#pragma unroll
  for (int nt = 0; nt < NT2; ++nt) bias2[nt] = (nt * 16 + l15 < OUTW) ? b2[nt * 16 + l15] : 0.f;

  for (int g = wid; g < NG; g += nwaves) {
    const int n0 = g * 16;
    const int rA = n0 + l15;

    f32x4 acc[4];
#pragma unroll
    for (int nt = 0; nt < 4; ++nt) { acc[nt][0] = 0.f; acc[nt][1] = 0.f; acc[nt][2] = 0.f; acc[nt][3] = 0.f; }

#pragma unroll
    for (int kk = 0; kk < KT1; ++kk) {
      f16x8 a;
      if (STAGE == 0) {
        if (kk == 0) {
          a = fzero8();
          if (lg == 0) {
#pragma unroll
            for (int j = 0; j < 5; ++j) a[j] = (f16)xraw[(size_t)rA * 5 + j];
          }
        } else {
          a = *(const f16x8*)(aggh + (size_t)rA * 64 + (kk - 1) * 32 + lg * 8);
        }
      } else {
        a = (kk < 2) ? *(const f16x8*)(xh + (size_t)rA * 64 + kk * 32 + lg * 8)
                     : *(const f16x8*)(aggh + (size_t)rA * 64 + (kk - 2) * 32 + lg * 8);
      }
#pragma unroll
      for (int nt = 0; nt < 4; ++nt) acc[nt] = mfma16(a, B1f[kk][nt], acc[nt]);
    }
#pragma unroll
    for (int nt = 0; nt < 4; ++nt)
#pragma unroll
      for (int r = 0; r < 4; ++r) {
        float h = fmaxf(acc[nt][r] + bias1[nt], 0.f);
        h1s[wave][lg * 4 + r][nt * 16 + l15] = (f16)h;
      }

    f32x4 out[NT2];
#pragma unroll
    for (int nt = 0; nt < NT2; ++nt) { out[nt][0] = 0.f; out[nt][1] = 0.f; out[nt][2] = 0.f; out[nt][3] = 0.f; }
#pragma unroll
    for (int kk = 0; kk < 2; ++kk) {
      f16x8 hf = *(const f16x8*)&h1s[wave][l15][kk * 32 + lg * 8];
#pragma unroll
      for (int nt = 0; nt < NT2; ++nt) out[nt] = mfma16(hf, B2f[kk][nt], out[nt]);
    }
#pragma unroll
    for (int r = 0; r < 4; ++r) {
      const int row = n0 + lg * 4 + r;
#pragma unroll
      for (int nt = 0; nt < NT2; ++nt) {
        const int col = nt * 16 + l15;
        float v = out[nt][r] + bias2[nt];
        if (STAGE == 0) {
          xl[(size_t)row * 64 + col] = v;
          xho[(size_t)row * 64 + col] = (f16)v;
        } else if (STAGE == 1) {
          float nv = xl[(size_t)row * 64 + col] + v;
          xl[(size_t)row * 64 + col] = nv;
          xho[(size_t)row * 64 + col] = (f16)nv;
        } else {
          if (col < OUTW) outp[(size_t)row * OUTW + col] = v;
        }
      }
    }
  }
}

// ---------------- launch ----------------

extern "C" void kernel_launch(void* const* d_in, const int* in_sizes, int n_in,
                              void* d_out, int out_size, void* d_ws, size_t ws_size,
                              hipStream_t stream) {
  const float* x  = (const float*)d_in[0];
  const int* ei   = (const int*)d_in[1];
  const float* ea = (const float*)d_in[2];
  const float* enc_e_b1 = (const float*)d_in[4];
  const float* enc_e_b2 = (const float*)d_in[6];
  const float* enc_n_b1 = (const float*)d_in[8];
  const float* enc_n_b2 = (const float*)d_in[10];
  const float* proc_e_b1 = (const float*)d_in[12];
  const float* proc_e_b2 = (const float*)d_in[14];
  const float* proc_n_b1 = (const float*)d_in[16];
  const float* proc_n_b2 = (const float*)d_in[18];
  const float* dec_e_b1 = (const float*)d_in[20];
  const float* dec_e_b2 = (const float*)d_in[22];
  const float* dec_n_b1 = (const float*)d_in[24];
  const float* dec_n_b2 = (const float*)d_in[26];

  const int* src = ei;
  const int* dst = ei + NE;

  // workspace layout (~174 MB total; R2 proved >= 263 MB available)
  char* p = (char*)d_ws;
  f16* el    = (f16*)p;   p += (size_t)NE * 64 * 2;   // 102.4 MB
  f16* Aenc  = (f16*)p;   p += (size_t)NE * 16 * 2;   // 25.6 MB
  float* xl  = (float*)p; p += (size_t)NN * 64 * 4;   // 12.8 MB
  f16* xh    = (f16*)p;   p += (size_t)NN * 64 * 2;   // 6.4 MB
  f16* aggh  = (f16*)p;   p += (size_t)NN * 64 * 2;   // 6.4 MB
  float* M   = (float*)p; p += (size_t)NN * 64 * 4;   // 12.8 MB running mean of el (f32)
  int* cnt   = (int*)p;   p += (size_t)NN * 4;
  int* off   = (int*)p;   p += (size_t)(NN + 1) * 4;
  int* cur   = (int*)p;   p += (size_t)NN * 4;
  float* inv = (float*)p; p += (size_t)NN * 4;
  int* psrc  = (int*)p;   p += (size_t)NE * 4;
  int* pdst  = (int*)p;   p += (size_t)NE * 4;
  f16* wb    = (f16*)p;   p += 70656 * 2;
  f16* W1T_ence = wb + 0;
  f16* W2T_ence = wb + 2048;
  f16* W1T_encn = wb + 6144;
  f16* W2T_encn = wb + 12288;
  f16* W1T_proce = wb + 16384;
  f16* W2T_proce = wb + 28672;
  f16* W1T_procn = wb + 32768;
  f16* W2T_procn = wb + 40960;
  f16* W1T_dece = wb + 45056;
  f16* W2T_dece = wb + 57344;
  f16* W1T_decn = wb + 61440;
  f16* W2T_decn = wb + 69632;

  hipMemsetAsync(cnt, 0, (size_t)NN * 4, stream);
  hipMemsetAsync(wb, 0, 70656 * 2, stream);

  count_kernel<<<(NE + 255) / 256, 256, 0, stream>>>(dst, cnt);
  scan_kernel<<<1, 1024, 0, stream>>>(cnt, off, cur, inv);
  scatter_pack<<<(NE + 255) / 256, 256, 0, stream>>>(x, ea, src, dst, cur, psrc, pdst, Aenc);

  PrepPtrs P;
  P.W[0]  = (const float*)d_in[3];   // enc_e_w1
  P.W[1]  = (const float*)d_in[5];   // enc_e_w2
  P.W[2]  = (const float*)d_in[7];   // enc_n_w1 (raw part)
  P.W[3]  = (const float*)d_in[7];   // enc_n_w1 (agg part)
  P.W[4]  = (const float*)d_in[9];   // enc_n_w2
  P.W[5]  = (const float*)d_in[11];  // proc_e_w1
  P.W[6]  = (const float*)d_in[13];  // proc_e_w2
  P.W[7]  = (const float*)d_in[15];  // proc_n_w1
  P.W[8]  = (const float*)d_in[17];  // proc_n_w2
  P.W[9]  = (const float*)d_in[19];  // dec_e_w1
  P.W[10] = (const float*)d_in[21];  // dec_e_w2
  P.W[11] = (const float*)d_in[23];  // dec_n_w1
  P.W[12] = (const float*)d_in[25];  // dec_n_w2
  prep_all<<<13, 256, 0, stream>>>(P, wb);

  const int AGG_BLK = (NN + 3) / 4;

  // ---- encoder ----
  edge_mlp_kernel<0, 1><<<2048, 256, 0, stream>>>(Aenc, xh, el, el, psrc, pdst,
                                                  W1T_ence, W2T_ence, enc_e_b1, enc_e_b2);
  agg_kernel<0><<<AGG_BLK, 256, 0, stream>>>(el, off, inv, M, aggh);
  node_mlp_kernel<0, 3, 4, 64><<<256, 256, 0, stream>>>(x, xh, aggh, W1T_encn, W2T_encn,
                                                        enc_n_b1, enc_n_b2, xl, xh, (float*)d_out);
  // ---- 2 processor rounds (shared weights, residuals) ----
  for (int r = 0; r < 2; ++r) {
    edge_mlp_kernel<1, 6><<<2048, 256, 0, stream>>>(Aenc, xh, el, el, psrc, pdst,
                                                    W1T_proce, W2T_proce, proc_e_b1, proc_e_b2);
    agg_kernel<1><<<AGG_BLK, 256, 0, stream>>>(el, off, inv, M, aggh);
    node_mlp_kernel<1, 4, 4, 64><<<256, 256, 0, stream>>>(x, xh, aggh, W1T_procn, W2T_procn,
                                                          proc_n_b1, proc_n_b2, xl, xh, (float*)d_out);
  }
  // ---- decoder (el += ed in place; agg = mean(el') - M) ----
  edge_mlp_kernel<1, 6><<<2048, 256, 0, stream>>>(Aenc, xh, el, el, psrc, pdst,
                                                  W1T_dece, W2T_dece, dec_e_b1, dec_e_b2);
  agg_kernel<2><<<AGG_BLK, 256, 0, stream>>>(el, off, inv, M, aggh);
  node_mlp_kernel<2, 4, 1, 7><<<256, 256, 0, stream>>>(x, xh, aggh, W1T_decn, W2T_decn,
                                                       dec_n_b1, dec_n_b2, xl, xh, (float*)d_out);
}

// Round 5
// 1034.744 us; speedup vs baseline: 1.0404x; 1.0266x over previous
//
#include <hip/hip_runtime.h>

#define NN 50000
#define NE 800000

typedef _Float16 f16;
typedef _Float16 f16x8 __attribute__((ext_vector_type(8)));
typedef _Float16 f16x4 __attribute__((ext_vector_type(4)));
typedef float f32x4 __attribute__((ext_vector_type(4)));

__device__ __forceinline__ f16x8 fzero8() {
  f16x8 v;
#pragma unroll
  for (int i = 0; i < 8; ++i) v[i] = (f16)0.f;
  return v;
}

__device__ __forceinline__ f32x4 mfma16(f16x8 a, f16x8 b, f32x4 c) {
  return __builtin_amdgcn_mfma_f32_16x16x32_f16(a, b, c, 0, 0, 0);
}

// ---------------- prep kernels ----------------

__global__ void count_kernel(const int* __restrict__ dst, int* __restrict__ cnt) {
  int e = blockIdx.x * 256 + threadIdx.x;
  if (e < NE) atomicAdd(&cnt[dst[e]], 1);
}

// single-block exclusive scan over cnt -> off/cur, plus inv = 1/max(cnt,1)
__global__ void scan_kernel(const int* __restrict__ cnt, int* __restrict__ off,
                            int* __restrict__ cur, float* __restrict__ inv) {
  __shared__ int part[1024];
  const int t = threadIdx.x;
  const int CH = (NN + 1023) / 1024;
  const int i0 = t * CH, i1 = (i0 + CH < NN) ? i0 + CH : NN;
  int s = 0;
  for (int i = i0; i < i1; ++i) s += cnt[i];
  part[t] = s;
  __syncthreads();
  for (int d = 1; d < 1024; d <<= 1) {
    int v = (t >= d) ? part[t - d] : 0;
    __syncthreads();
    part[t] += v;
    __syncthreads();
  }
  int base = (t > 0) ? part[t - 1] : 0;
  for (int i = i0; i < i1; ++i) {
    off[i] = base;
    cur[i] = base;
    inv[i] = 1.0f / fmaxf((float)cnt[i], 1.0f);
    base += cnt[i];
  }
  if (t == 1023) off[NN] = NE;
}

// scatter edges into dst-sorted order; also build packed encoder rows
// [x_src(5) | x_dst(5) | ea(4) | 0 0] f16[16] at the permuted position.
__global__ void scatter_pack(const float* __restrict__ x, const float* __restrict__ ea,
                             const int* __restrict__ src, const int* __restrict__ dst,
                             int* __restrict__ cur, int* __restrict__ psrc,
                             int* __restrict__ pdst, f16* __restrict__ A) {
  int e = blockIdx.x * 256 + threadIdx.x;
  if (e >= NE) return;
  int s = src[e], d = dst[e];
  int pos = atomicAdd(&cur[d], 1);
  psrc[pos] = s;
  pdst[pos] = d;
  f16 row[16];
#pragma unroll
  for (int i = 0; i < 5; ++i) { row[i] = (f16)x[s * 5 + i]; row[5 + i] = (f16)x[d * 5 + i]; }
#pragma unroll
  for (int i = 0; i < 4; ++i) row[10 + i] = (f16)ea[e * 4 + i];
  row[14] = (f16)0.f; row[15] = (f16)0.f;
  __builtin_nontemporal_store(*(f16x8*)row, (f16x8*)(A + (size_t)pos * 16));
  __builtin_nontemporal_store(*(f16x8*)(row + 8), (f16x8*)(A + (size_t)pos * 16 + 8));
}

// all 13 weight transposes in one launch; block b handles matrix b
struct PrepPtrs { const float* W[13]; };
__global__ void prep_all(PrepPtrs P, f16* __restrict__ out) {
  const int Nw[13]   = {64,64,64,64,64,64,64,64,64,64,64,64,7};
  const int Kd[13]   = {32,64,96,96,64,192,64,128,64,192,64,128,64};
  const int ks[13]   = {0,0,0,5,0,0,0,0,0,0,0,0,0};
  const int kd[13]   = {0,0,0,32,0,0,0,0,0,0,0,0,0};
  const int klen[13] = {14,64,5,64,64,192,64,128,64,192,64,128,64};
  const int nc[13]   = {64,64,64,64,64,64,64,64,64,64,64,64,7};
  const int ofs[13]  = {0,2048,6144,6144,12288,16384,28672,32768,40960,45056,57344,61440,69632};
  const int m = blockIdx.x;
  const float* W = P.W[m];
  const int tot = klen[m] * nc[m];
  for (int idx = threadIdx.x; idx < tot; idx += 256) {
    int kk = idx / nc[m], n = idx % nc[m];
    out[ofs[m] + n * Kd[m] + kd[m] + kk] = (f16)W[(ks[m] + kk) * Nw[m] + n];
  }
}

// ---------------- edge MLP (fused segmented aggregation) ----------------
// STAGE: 0=encoder (A from packed Aenc, write el, agg += el)
//        1=processor (A=[xh[src]|xh[dst]|el], el += ed in place, agg += ed)
//        2=decoder   (A same as proc, NO el write, agg += ed)
// Edges are dst-sorted; chunked wave->group mapping; per-group segmented
// reduction with one coalesced 64-lane f32 atomicAdd per dst segment.
template <int STAGE, int KT1, int IPW>
__global__ void edge_mlp_kernel(const f16* __restrict__ Aenc,
                                const f16* __restrict__ xh,
                                const f16* elr, f16* elw,
                                const int* __restrict__ psrc,
                                const int* __restrict__ pdst,
                                const f16* __restrict__ B1,
                                const f16* __restrict__ B2,
                                const float* __restrict__ b1,
                                const float* __restrict__ b2,
                                float* __restrict__ agg) {
  constexpr int K1 = KT1 * 32;
  __shared__ __align__(16) f16 h1s[4][16][72];
  const int wave = threadIdx.x >> 6;
  const int lane = threadIdx.x & 63;
  const int l15 = lane & 15, lg = lane >> 4;
  const int wid = blockIdx.x * 4 + wave;
  const int NG = NE / 16;

  f16x8 B1f[KT1][4];
#pragma unroll
  for (int kk = 0; kk < KT1; ++kk)
#pragma unroll
    for (int nt = 0; nt < 4; ++nt)
      B1f[kk][nt] = *(const f16x8*)(B1 + (nt * 16 + l15) * K1 + kk * 32 + lg * 8);
  f16x8 B2f[2][4];
#pragma unroll
  for (int kk = 0; kk < 2; ++kk)
#pragma unroll
    for (int nt = 0; nt < 4; ++nt)
      B2f[kk][nt] = *(const f16x8*)(B2 + (nt * 16 + l15) * 64 + kk * 32 + lg * 8);
  float bias1[4], bias2[4];
#pragma unroll
  for (int nt = 0; nt < 4; ++nt) { bias1[nt] = b1[nt * 16 + l15]; bias2[nt] = b2[nt * 16 + l15]; }

  const int g0 = wid * IPW;
  const int g1 = (g0 + IPW < NG) ? g0 + IPW : NG;

  for (int g = g0; g < g1; ++g) {
    const int e0 = g * 16;
    const int erA = e0 + l15;
    const int d = pdst[erA];
    int s = 0;
    if (STAGE != 0) s = psrc[erA];

    f32x4 acc[4];
#pragma unroll
    for (int nt = 0; nt < 4; ++nt) { acc[nt][0] = 0.f; acc[nt][1] = 0.f; acc[nt][2] = 0.f; acc[nt][3] = 0.f; }

    f16x8 o0 = fzero8(), o1 = fzero8();  // el fragment kept for residual
    if (STAGE == 0) {
      f16x8 a = fzero8();
      if (lg < 2) a = *(const f16x8*)(Aenc + (size_t)erA * 16 + lg * 8);
#pragma unroll
      for (int nt = 0; nt < 4; ++nt) acc[nt] = mfma16(a, B1f[0][nt], acc[nt]);
    } else {
#pragma unroll
      for (int kk = 0; kk < KT1; ++kk) {
        f16x8 a;
        if (kk < 2) {
          a = *(const f16x8*)(xh + (size_t)s * 64 + kk * 32 + lg * 8);
        } else if (kk < 4) {
          a = *(const f16x8*)(xh + (size_t)d * 64 + (kk - 2) * 32 + lg * 8);
        } else {
          a = *(const f16x8*)(elr + (size_t)erA * 64 + (kk - 4) * 32 + lg * 8);
          if (kk == 4) o0 = a; else o1 = a;
        }
#pragma unroll
        for (int nt = 0; nt < 4; ++nt) acc[nt] = mfma16(a, B1f[kk][nt], acc[nt]);
      }
    }
    // bias + relu, stage h1 to LDS (C-layout -> A-layout); per-wave slice, no barrier
#pragma unroll
    for (int nt = 0; nt < 4; ++nt)
#pragma unroll
      for (int r = 0; r < 4; ++r) {
        float h = fmaxf(acc[nt][r] + bias1[nt], 0.f);
        h1s[wave][lg * 4 + r][nt * 16 + l15] = (f16)h;
      }

    f32x4 out[4];
#pragma unroll
    for (int nt = 0; nt < 4; ++nt) { out[nt][0] = 0.f; out[nt][1] = 0.f; out[nt][2] = 0.f; out[nt][3] = 0.f; }
#pragma unroll
    for (int kk = 0; kk < 2; ++kk) {
      f16x8 hf = *(const f16x8*)&h1s[wave][l15][kk * 32 + lg * 8];
#pragma unroll
      for (int nt = 0; nt < 4; ++nt) out[nt] = mfma16(hf, B2f[kk][nt], out[nt]);
    }

    // stage output ed/el (bias added) back to LDS rows
#pragma unroll
    for (int nt = 0; nt < 4; ++nt)
#pragma unroll
      for (int r = 0; r < 4; ++r)
        h1s[wave][lg * 4 + r][nt * 16 + l15] = (f16)(out[nt][r] + bias2[nt]);

    // global el write (encoder: fresh; proc: in-place residual; decoder: none)
    if (STAGE != 2) {
      f16x8 v0 = *(const f16x8*)&h1s[wave][l15][lg * 8];
      f16x8 v1 = *(const f16x8*)&h1s[wave][l15][32 + lg * 8];
      f16* p0 = elw + (size_t)erA * 64 + lg * 8;
      if (STAGE == 1) {
        f16x8 n0, n1;
#pragma unroll
        for (int j = 0; j < 8; ++j) {
          n0[j] = (f16)((float)o0[j] + (float)v0[j]);
          n1[j] = (f16)((float)o1[j] + (float)v1[j]);
        }
        __builtin_nontemporal_store(n0, (f16x8*)p0);
        __builtin_nontemporal_store(n1, (f16x8*)(p0 + 32));
      } else {
        __builtin_nontemporal_store(v0, (f16x8*)p0);
        __builtin_nontemporal_store(v1, (f16x8*)(p0 + 32));
      }
    }

    // fused segmented reduction: lane = column, walk 16 sorted rows,
    // one coalesced 64-lane atomicAdd per dst segment (dst is wave-uniform).
    {
      float racc = 0.f;
      int dprev = __shfl(d, 0);
#pragma unroll
      for (int row = 0; row < 16; ++row) {
        const int dn = __shfl(d, row);
        const float v = (float)h1s[wave][row][lane];
        if (dn != dprev) {
          atomicAdd(agg + (size_t)dprev * 64 + lane, racc);
          racc = 0.f;
          dprev = dn;
        }
        racc += v;
      }
      atomicAdd(agg + (size_t)dprev * 64 + lane, racc);
    }
  }
}

// ---------------- node MLP (fused mean-finish) ----------------
// STAGE: 0=encoder (A=[x_raw(5,pad32)|agg*inv], out: xl=v, xh=f16(v))
//        1=processor (A=[xh|agg*inv], xl += v, xh mirror)
//        2=decoder   (A=[xh|agg*inv], write d_out[N][7])
template <int STAGE, int KT1, int NT2, int OUTW>
__global__ void node_mlp_kernel(const float* __restrict__ xraw,
                                const f16* xh,
                                const float* __restrict__ agg,
                                const float* __restrict__ inv,
                                const f16* __restrict__ B1,
                                const f16* __restrict__ B2,
                                const float* __restrict__ b1,
                                const float* __restrict__ b2,
                                float* __restrict__ xl,
                                f16* xho,
                                float* __restrict__ outp) {
  constexpr int K1 = KT1 * 32;
  __shared__ __align__(16) f16 h1s[4][16][72];
  const int wave = threadIdx.x >> 6;
  const int lane = threadIdx.x & 63;
  const int l15 = lane & 15, lg = lane >> 4;
  const int nwaves = gridDim.x * 4;
  const int wid = blockIdx.x * 4 + wave;
  const int NG = NN / 16;

  f16x8 B1f[KT1][4];
#pragma unroll
  for (int kk = 0; kk < KT1; ++kk)
#pragma unroll
    for (int nt = 0; nt < 4; ++nt)
      B1f[kk][nt] = *(const f16x8*)(B1 + (nt * 16 + l15) * K1 + kk * 32 + lg * 8);
  f16x8 B2f[2][NT2];
#pragma unroll
  for (int kk = 0; kk < 2; ++kk)
#pragma unroll
    for (int nt = 0; nt < NT2; ++nt)
      B2f[kk][nt] = *(const f16x8*)(B2 + (nt * 16 + l15) * 64 + kk * 32 + lg * 8);
  float bias1[4], bias2[NT2];
#pragma unroll
  for (int nt = 0; nt < 4; ++nt) bias1[nt] = b1[nt * 16 + l15];
#pragma unroll
  for (int nt = 0; nt < NT2; ++nt) bias2[nt] = (nt * 16 + l15 < OUTW) ? b2[nt * 16 + l15] : 0.f;

  for (int g = wid; g < NG; g += nwaves) {
    const int n0 = g * 16;
    const int rA = n0 + l15;
    const float iv = inv[rA];

    f32x4 acc[4];
#pragma unroll
    for (int nt = 0; nt < 4; ++nt) { acc[nt][0] = 0.f; acc[nt][1] = 0.f; acc[nt][2] = 0.f; acc[nt][3] = 0.f; }

#pragma unroll
    for (int kk = 0; kk < KT1; ++kk) {
      f16x8 a;
      if (STAGE == 0 && kk == 0) {
        a = fzero8();
        if (lg == 0) {
#pragma unroll
          for (int j = 0; j < 5; ++j) a[j] = (f16)xraw[(size_t)rA * 5 + j];
        }
      } else if (STAGE != 0 && kk < 2) {
        a = *(const f16x8*)(xh + (size_t)rA * 64 + kk * 32 + lg * 8);
      } else {
        const int ko = (STAGE == 0) ? (kk - 1) : (kk - 2);
        const float* ap = agg + (size_t)rA * 64 + ko * 32 + lg * 8;
        f32x4 a0 = *(const f32x4*)ap;
        f32x4 a1 = *(const f32x4*)(ap + 4);
#pragma unroll
        for (int j = 0; j < 4; ++j) { a[j] = (f16)(a0[j] * iv); a[4 + j] = (f16)(a1[j] * iv); }
      }
#pragma unroll
      for (int nt = 0; nt < 4; ++nt) acc[nt] = mfma16(a, B1f[kk][nt], acc[nt]);
    }
#pragma unroll
    for (int nt = 0; nt < 4; ++nt)
#pragma unroll
      for (int r = 0; r < 4; ++r) {
        float h = fmaxf(acc[nt][r] + bias1[nt], 0.f);
        h1s[wave][lg * 4 + r][nt * 16 + l15] = (f16)h;
      }

    f32x4 out[NT2];
#pragma unroll
    for (int nt = 0; nt < NT2; ++nt) { out[nt][0] = 0.f; out[nt][1] = 0.f; out[nt][2] = 0.f; out[nt][3] = 0.f; }
#pragma unroll
    for (int kk = 0; kk < 2; ++kk) {
      f16x8 hf = *(const f16x8*)&h1s[wave][l15][kk * 32 + lg * 8];
#pragma unroll
      for (int nt = 0; nt < NT2; ++nt) out[nt] = mfma16(hf, B2f[kk][nt], out[nt]);
    }
#pragma unroll
    for (int r = 0; r < 4; ++r) {
      const int row = n0 + lg * 4 + r;
#pragma unroll
      for (int nt = 0; nt < NT2; ++nt) {
        const int col = nt * 16 + l15;
        float v = out[nt][r] + bias2[nt];
        if (STAGE == 0) {
          xl[(size_t)row * 64 + col] = v;
          xho[(size_t)row * 64 + col] = (f16)v;
        } else if (STAGE == 1) {
          float nv = xl[(size_t)row * 64 + col] + v;
          xl[(size_t)row * 64 + col] = nv;
          xho[(size_t)row * 64 + col] = (f16)nv;
        } else {
          if (col < OUTW) outp[(size_t)row * OUTW + col] = v;
        }
      }
    }
  }
}

// ---------------- launch ----------------

extern "C" void kernel_launch(void* const* d_in, const int* in_sizes, int n_in,
                              void* d_out, int out_size, void* d_ws, size_t ws_size,
                              hipStream_t stream) {
  const float* x  = (const float*)d_in[0];
  const int* ei   = (const int*)d_in[1];
  const float* ea = (const float*)d_in[2];
  const float* enc_e_b1 = (const float*)d_in[4];
  const float* enc_e_b2 = (const float*)d_in[6];
  const float* enc_n_b1 = (const float*)d_in[8];
  const float* enc_n_b2 = (const float*)d_in[10];
  const float* proc_e_b1 = (const float*)d_in[12];
  const float* proc_e_b2 = (const float*)d_in[14];
  const float* proc_n_b1 = (const float*)d_in[16];
  const float* proc_n_b2 = (const float*)d_in[18];
  const float* dec_e_b1 = (const float*)d_in[20];
  const float* dec_e_b2 = (const float*)d_in[22];
  const float* dec_n_b1 = (const float*)d_in[24];
  const float* dec_n_b2 = (const float*)d_in[26];

  const int* src = ei;
  const int* dst = ei + NE;

  // workspace layout (~167 MB total; R2 proved >= 263 MB available)
  char* p = (char*)d_ws;
  f16* el    = (f16*)p;   p += (size_t)NE * 64 * 2;   // 102.4 MB
  f16* Aenc  = (f16*)p;   p += (size_t)NE * 16 * 2;   // 25.6 MB
  float* xl  = (float*)p; p += (size_t)NN * 64 * 4;   // 12.8 MB
  f16* xh    = (f16*)p;   p += (size_t)NN * 64 * 2;   // 6.4 MB
  float* agg = (float*)p; p += (size_t)NN * 64 * 4;   // 12.8 MB f32 atomic accumulator
  int* cnt   = (int*)p;   p += (size_t)NN * 4;
  int* off   = (int*)p;   p += (size_t)(NN + 1) * 4;
  int* cur   = (int*)p;   p += (size_t)NN * 4;
  float* inv = (float*)p; p += (size_t)NN * 4;
  int* psrc  = (int*)p;   p += (size_t)NE * 4;
  int* pdst  = (int*)p;   p += (size_t)NE * 4;
  f16* wb    = (f16*)p;   p += 70656 * 2;
  f16* W1T_ence = wb + 0;
  f16* W2T_ence = wb + 2048;
  f16* W1T_encn = wb + 6144;
  f16* W2T_encn = wb + 12288;
  f16* W1T_proce = wb + 16384;
  f16* W2T_proce = wb + 28672;
  f16* W1T_procn = wb + 32768;
  f16* W2T_procn = wb + 40960;
  f16* W1T_dece = wb + 45056;
  f16* W2T_dece = wb + 57344;
  f16* W1T_decn = wb + 61440;
  f16* W2T_decn = wb + 69632;

  hipMemsetAsync(cnt, 0, (size_t)NN * 4, stream);
  hipMemsetAsync(wb, 0, 70656 * 2, stream);

  count_kernel<<<(NE + 255) / 256, 256, 0, stream>>>(dst, cnt);
  scan_kernel<<<1, 1024, 0, stream>>>(cnt, off, cur, inv);
  scatter_pack<<<(NE + 255) / 256, 256, 0, stream>>>(x, ea, src, dst, cur, psrc, pdst, Aenc);

  PrepPtrs P;
  P.W[0]  = (const float*)d_in[3];   // enc_e_w1
  P.W[1]  = (const float*)d_in[5];   // enc_e_w2
  P.W[2]  = (const float*)d_in[7];   // enc_n_w1 (raw part)
  P.W[3]  = (const float*)d_in[7];   // enc_n_w1 (agg part)
  P.W[4]  = (const float*)d_in[9];   // enc_n_w2
  P.W[5]  = (const float*)d_in[11];  // proc_e_w1
  P.W[6]  = (const float*)d_in[13];  // proc_e_w2
  P.W[7]  = (const float*)d_in[15];  // proc_n_w1
  P.W[8]  = (const float*)d_in[17];  // proc_n_w2
  P.W[9]  = (const float*)d_in[19];  // dec_e_w1
  P.W[10] = (const float*)d_in[21];  // dec_e_w2
  P.W[11] = (const float*)d_in[23];  // dec_n_w1
  P.W[12] = (const float*)d_in[25];  // dec_n_w2
  prep_all<<<13, 256, 0, stream>>>(P, wb);

  // edge grid: chunked mapping, 4 waves/block, IPW groups/wave
  constexpr int IPW = 6;
  const int NG = NE / 16;                        // 50000
  const int EDGE_BLK = (NG + 4 * IPW - 1) / (4 * IPW);  // 2084
  const size_t AGG_BYTES = (size_t)NN * 64 * 4;

  // ---- encoder ----
  hipMemsetAsync(agg, 0, AGG_BYTES, stream);
  edge_mlp_kernel<0, 1, IPW><<<EDGE_BLK, 256, 0, stream>>>(Aenc, xh, el, el, psrc, pdst,
                                                           W1T_ence, W2T_ence, enc_e_b1, enc_e_b2, agg);
  node_mlp_kernel<0, 3, 4, 64><<<256, 256, 0, stream>>>(x, xh, agg, inv, W1T_encn, W2T_encn,
                                                        enc_n_b1, enc_n_b2, xl, xh, (float*)d_out);
  // ---- 2 processor rounds (shared weights, residuals) ----
  for (int r = 0; r < 2; ++r) {
    hipMemsetAsync(agg, 0, AGG_BYTES, stream);
    edge_mlp_kernel<1, 6, IPW><<<EDGE_BLK, 256, 0, stream>>>(Aenc, xh, el, el, psrc, pdst,
                                                             W1T_proce, W2T_proce, proc_e_b1, proc_e_b2, agg);
    node_mlp_kernel<1, 4, 4, 64><<<256, 256, 0, stream>>>(x, xh, agg, inv, W1T_procn, W2T_procn,
                                                          proc_n_b1, proc_n_b2, xl, xh, (float*)d_out);
  }
  // ---- decoder (no el write; agg of ed only) ----
  hipMemsetAsync(agg, 0, AGG_BYTES, stream);
  edge_mlp_kernel<2, 6, IPW><<<EDGE_BLK, 256, 0, stream>>>(Aenc, xh, el, el, psrc, pdst,
                                                           W1T_dece, W2T_dece, dec_e_b1, dec_e_b2, agg);
  node_mlp_kernel<2, 4, 1, 7><<<256, 256, 0, stream>>>(x, xh, agg, inv, W1T_decn, W2T_decn,
                                                       dec_n_b1, dec_n_b2, xl, xh, (float*)d_out);
}

// Round 6
// 1021.689 us; speedup vs baseline: 1.0537x; 1.0128x over previous
//
#include <hip/hip_runtime.h>

#define NN 50000
#define NE 800000

typedef _Float16 f16;
typedef _Float16 f16x8 __attribute__((ext_vector_type(8)));
typedef float f32x4 __attribute__((ext_vector_type(4)));

__device__ __forceinline__ f16x8 fzero8() {
  f16x8 v;
#pragma unroll
  for (int i = 0; i < 8; ++i) v[i] = (f16)0.f;
  return v;
}

__device__ __forceinline__ f32x4 mfma16(f16x8 a, f16x8 b, f32x4 c) {
  return __builtin_amdgcn_mfma_f32_16x16x32_f16(a, b, c, 0, 0, 0);
}

// ---------------- prep kernels ----------------

__global__ void count_kernel(const int* __restrict__ dst, int* __restrict__ cnt) {
  int e = blockIdx.x * 256 + threadIdx.x;
  if (e < NE) atomicAdd(&cnt[dst[e]], 1);
}

// single-block exclusive scan over cnt -> off/cur, plus inv = 1/max(cnt,1)
__global__ void scan_kernel(const int* __restrict__ cnt, int* __restrict__ off,
                            int* __restrict__ cur, float* __restrict__ inv) {
  __shared__ int part[1024];
  const int t = threadIdx.x;
  const int CH = (NN + 1023) / 1024;
  const int i0 = t * CH, i1 = (i0 + CH < NN) ? i0 + CH : NN;
  int s = 0;
  for (int i = i0; i < i1; ++i) s += cnt[i];
  part[t] = s;
  __syncthreads();
  for (int d = 1; d < 1024; d <<= 1) {
    int v = (t >= d) ? part[t - d] : 0;
    __syncthreads();
    part[t] += v;
    __syncthreads();
  }
  int base = (t > 0) ? part[t - 1] : 0;
  for (int i = i0; i < i1; ++i) {
    off[i] = base;
    cur[i] = base;
    inv[i] = 1.0f / fmaxf((float)cnt[i], 1.0f);
    base += cnt[i];
  }
  if (t == 1023) off[NN] = NE;
}

// scatter edges into dst-sorted order; also build packed encoder rows
// [x_src(5) | x_dst(5) | ea(4) | 0 0] f16[16] at the permuted position.
__global__ void scatter_pack(const float* __restrict__ x, const float* __restrict__ ea,
                             const int* __restrict__ src, const int* __restrict__ dst,
                             int* __restrict__ cur, int* __restrict__ psrc,
                             int* __restrict__ pdst, f16* __restrict__ A) {
  int e = blockIdx.x * 256 + threadIdx.x;
  if (e >= NE) return;
  int s = src[e], d = dst[e];
  int pos = atomicAdd(&cur[d], 1);
  psrc[pos] = s;
  pdst[pos] = d;
  f16 row[16];
#pragma unroll
  for (int i = 0; i < 5; ++i) { row[i] = (f16)x[s * 5 + i]; row[5 + i] = (f16)x[d * 5 + i]; }
#pragma unroll
  for (int i = 0; i < 4; ++i) row[10 + i] = (f16)ea[e * 4 + i];
  row[14] = (f16)0.f; row[15] = (f16)0.f;
  *(f16x8*)(A + (size_t)pos * 16) = *(f16x8*)row;
  *(f16x8*)(A + (size_t)pos * 16 + 8) = *(f16x8*)(row + 8);
}

// all 13 weight transposes in one launch; block b handles matrix b
struct PrepPtrs { const float* W[13]; };
__global__ void prep_all(PrepPtrs P, f16* __restrict__ out) {
  const int Nw[13]   = {64,64,64,64,64,64,64,64,64,64,64,64,7};
  const int Kd[13]   = {32,64,96,96,64,192,64,128,64,192,64,128,64};
  const int ks[13]   = {0,0,0,5,0,0,0,0,0,0,0,0,0};
  const int kd[13]   = {0,0,0,32,0,0,0,0,0,0,0,0,0};
  const int klen[13] = {14,64,5,64,64,192,64,128,64,192,64,128,64};
  const int nc[13]   = {64,64,64,64,64,64,64,64,64,64,64,64,7};
  const int ofs[13]  = {0,2048,6144,6144,12288,16384,28672,32768,40960,45056,57344,61440,69632};
  const int m = blockIdx.x;
  const float* W = P.W[m];
  const int tot = klen[m] * nc[m];
  for (int idx = threadIdx.x; idx < tot; idx += 256) {
    int kk = idx / nc[m], n = idx % nc[m];
    out[ofs[m] + n * Kd[m] + kd[m] + kk] = (f16)W[(ks[m] + kk) * Nw[m] + n];
  }
}

// ---------------- edge MLP (fused segmented aggregation) ----------------
// STAGE: 0=encoder (A from packed Aenc, write el, agg += el)
//        1=processor (A=[xh[src]|xh[dst]|el], el += ed in place, agg += ed)
//        2=decoder   (A same as proc, NO el write, agg += ed)
// Edges are dst-sorted; strided wave->group mapping with index prefetch;
// per-group segmented reduction, one coalesced 64-lane atomicAdd per segment.
template <int STAGE, int KT1>
__global__ void edge_mlp_kernel(const f16* __restrict__ Aenc,
                                const f16* __restrict__ xh,
                                const f16* elr, f16* elw,
                                const int* __restrict__ psrc,
                                const int* __restrict__ pdst,
                                const f16* __restrict__ B1,
                                const f16* __restrict__ B2,
                                const float* __restrict__ b1,
                                const float* __restrict__ b2,
                                float* __restrict__ agg) {
  constexpr int K1 = KT1 * 32;
  __shared__ __align__(16) f16 h1s[4][16][72];
  const int wave = threadIdx.x >> 6;
  const int lane = threadIdx.x & 63;
  const int l15 = lane & 15, lg = lane >> 4;
  const int nwaves = gridDim.x * 4;
  const int wid = blockIdx.x * 4 + wave;
  const int NG = NE / 16;

  f16x8 B1f[KT1][4];
#pragma unroll
  for (int kk = 0; kk < KT1; ++kk)
#pragma unroll
    for (int nt = 0; nt < 4; ++nt)
      B1f[kk][nt] = *(const f16x8*)(B1 + (nt * 16 + l15) * K1 + kk * 32 + lg * 8);
  f16x8 B2f[2][4];
#pragma unroll
  for (int kk = 0; kk < 2; ++kk)
#pragma unroll
    for (int nt = 0; nt < 4; ++nt)
      B2f[kk][nt] = *(const f16x8*)(B2 + (nt * 16 + l15) * 64 + kk * 32 + lg * 8);
  float bias1[4], bias2[4];
#pragma unroll
  for (int nt = 0; nt < 4; ++nt) { bias1[nt] = b1[nt * 16 + l15]; bias2[nt] = b2[nt * 16 + l15]; }

  // index prefetch pipeline (dst always needed for fused agg; src only STAGE!=0)
  int sCur = 0, dCur = 0;
  if (wid < NG) {
    dCur = pdst[wid * 16 + l15];
    if (STAGE != 0) sCur = psrc[wid * 16 + l15];
  }

  for (int g = wid; g < NG; g += nwaves) {
    const int e0 = g * 16;
    const int erA = e0 + l15;

    const int s = sCur, d = dCur;
    {
      const int gN = g + nwaves;
      if (gN < NG) {
        dCur = pdst[gN * 16 + l15];
        if (STAGE != 0) sCur = psrc[gN * 16 + l15];
      }
    }

    f32x4 acc[4];
#pragma unroll
    for (int nt = 0; nt < 4; ++nt) { acc[nt][0] = 0.f; acc[nt][1] = 0.f; acc[nt][2] = 0.f; acc[nt][3] = 0.f; }

    f16x8 o0 = fzero8(), o1 = fzero8();  // el fragment kept for residual
    if (STAGE == 0) {
      f16x8 a = fzero8();
      if (lg < 2) a = *(const f16x8*)(Aenc + (size_t)erA * 16 + lg * 8);
#pragma unroll
      for (int nt = 0; nt < 4; ++nt) acc[nt] = mfma16(a, B1f[0][nt], acc[nt]);
    } else {
#pragma unroll
      for (int kk = 0; kk < KT1; ++kk) {
        f16x8 a;
        if (kk < 2) {
          a = *(const f16x8*)(xh + (size_t)s * 64 + kk * 32 + lg * 8);
        } else if (kk < 4) {
          a = *(const f16x8*)(xh + (size_t)d * 64 + (kk - 2) * 32 + lg * 8);
        } else {
          a = *(const f16x8*)(elr + (size_t)erA * 64 + (kk - 4) * 32 + lg * 8);
          if (kk == 4) o0 = a; else o1 = a;
        }
#pragma unroll
        for (int nt = 0; nt < 4; ++nt) acc[nt] = mfma16(a, B1f[kk][nt], acc[nt]);
      }
    }
    // bias + relu, stage h1 to LDS (C-layout -> A-layout); per-wave slice, no barrier
#pragma unroll
    for (int nt = 0; nt < 4; ++nt)
#pragma unroll
      for (int r = 0; r < 4; ++r) {
        float h = fmaxf(acc[nt][r] + bias1[nt], 0.f);
        h1s[wave][lg * 4 + r][nt * 16 + l15] = (f16)h;
      }

    f32x4 out[4];
#pragma unroll
    for (int nt = 0; nt < 4; ++nt) { out[nt][0] = 0.f; out[nt][1] = 0.f; out[nt][2] = 0.f; out[nt][3] = 0.f; }
#pragma unroll
    for (int kk = 0; kk < 2; ++kk) {
      f16x8 hf = *(const f16x8*)&h1s[wave][l15][kk * 32 + lg * 8];
#pragma unroll
      for (int nt = 0; nt < 4; ++nt) out[nt] = mfma16(hf, B2f[kk][nt], out[nt]);
    }

    // stage output ed (bias added) back to LDS rows
#pragma unroll
    for (int nt = 0; nt < 4; ++nt)
#pragma unroll
      for (int r = 0; r < 4; ++r)
        h1s[wave][lg * 4 + r][nt * 16 + l15] = (f16)(out[nt][r] + bias2[nt]);

    // global el write (encoder: fresh; proc: in-place residual; decoder: none)
    if (STAGE != 2) {
      f16x8 v0 = *(const f16x8*)&h1s[wave][l15][lg * 8];
      f16x8 v1 = *(const f16x8*)&h1s[wave][l15][32 + lg * 8];
      f16* p0 = elw + (size_t)erA * 64 + lg * 8;
      if (STAGE == 1) {
        f16x8 n0, n1;
#pragma unroll
        for (int j = 0; j < 8; ++j) {
          n0[j] = (f16)((float)o0[j] + (float)v0[j]);
          n1[j] = (f16)((float)o1[j] + (float)v1[j]);
        }
        *(f16x8*)p0 = n0;
        *(f16x8*)(p0 + 32) = n1;
      } else {
        *(f16x8*)p0 = v0;
        *(f16x8*)(p0 + 32) = v1;
      }
    }

    // fused segmented reduction: lane = column, walk 16 sorted rows,
    // one coalesced 64-lane atomicAdd per dst segment (dst is wave-uniform).
    {
      float racc = 0.f;
      int dprev = __shfl(d, 0);
#pragma unroll
      for (int row = 0; row < 16; ++row) {
        const int dn = __shfl(d, row);
        const float v = (float)h1s[wave][row][lane];
        if (dn != dprev) {
          atomicAdd(agg + (size_t)dprev * 64 + lane, racc);
          racc = 0.f;
          dprev = dn;
        }
        racc += v;
      }
      atomicAdd(agg + (size_t)dprev * 64 + lane, racc);
    }
  }
}

// ---------------- node MLP (fused mean-finish) ----------------
// STAGE: 0=encoder (A=[x_raw(5,pad32)|agg*inv], out: xl=v, xh=f16(v))
//        1=processor (A=[xh|agg*inv], xl += v, xh mirror)
//        2=decoder   (A=[xh|agg*inv], write d_out[N][7])
template <int STAGE, int KT1, int NT2, int OUTW>
__global__ void node_mlp_kernel(const float* __restrict__ xraw,
                                const f16* xh,
                                const float* __restrict__ agg,
                                const float* __restrict__ inv,
                                const f16* __restrict__ B1,
                                const f16* __restrict__ B2,
                                const float* __restrict__ b1,
                                const float* __restrict__ b2,
                                float* __restrict__ xl,
                                f16* xho,
                                float* __restrict__ outp) {
  constexpr int K1 = KT1 * 32;
  __shared__ __align__(16) f16 h1s[4][16][72];
  const int wave = threadIdx.x >> 6;
  const int lane = threadIdx.x & 63;
  const int l15 = lane & 15, lg = lane >> 4;
  const int nwaves = gridDim.x * 4;
  const int wid = blockIdx.x * 4 + wave;
  const int NG = NN / 16;

  f16x8 B1f[KT1][4];
#pragma unroll
  for (int kk = 0; kk < KT1; ++kk)
#pragma unroll
    for (int nt = 0; nt < 4; ++nt)
      B1f[kk][nt] = *(const f16x8*)(B1 + (nt * 16 + l15) * K1 + kk * 32 + lg * 8);
  f16x8 B2f[2][NT2];
#pragma unroll
  for (int kk = 0; kk < 2; ++kk)
#pragma unroll
    for (int nt = 0; nt < NT2; ++nt)
      B2f[kk][nt] = *(const f16x8*)(B2 + (nt * 16 + l15) * 64 + kk * 32 + lg * 8);
  float bias1[4], bias2[NT2];
#pragma unroll
  for (int nt = 0; nt < 4; ++nt) bias1[nt] = b1[nt * 16 + l15];
#pragma unroll
  for (int nt = 0; nt < NT2; ++nt) bias2[nt] = (nt * 16 + l15 < OUTW) ? b2[nt * 16 + l15] : 0.f;

  for (int g = wid; g < NG; g += nwaves) {
    const int n0 = g * 16;
    const int rA = n0 + l15;
    const float iv = inv[rA];

    f32x4 acc[4];
#pragma unroll
    for (int nt = 0; nt < 4; ++nt) { acc[nt][0] = 0.f; acc[nt][1] = 0.f; acc[nt][2] = 0.f; acc[nt][3] = 0.f; }

#pragma unroll
    for (int kk = 0; kk < KT1; ++kk) {
      f16x8 a;
      if (STAGE == 0 && kk == 0) {
        a = fzero8();
        if (lg == 0) {
#pragma unroll
          for (int j = 0; j < 5; ++j) a[j] = (f16)xraw[(size_t)rA * 5 + j];
        }
      } else if (STAGE != 0 && kk < 2) {
        a = *(const f16x8*)(xh + (size_t)rA * 64 + kk * 32 + lg * 8);
      } else {
        const int ko = (STAGE == 0) ? (kk - 1) : (kk - 2);
        const float* ap = agg + (size_t)rA * 64 + ko * 32 + lg * 8;
        f32x4 a0 = *(const f32x4*)ap;
        f32x4 a1 = *(const f32x4*)(ap + 4);
#pragma unroll
        for (int j = 0; j < 4; ++j) { a[j] = (f16)(a0[j] * iv); a[4 + j] = (f16)(a1[j] * iv); }
      }
#pragma unroll
      for (int nt = 0; nt < 4; ++nt) acc[nt] = mfma16(a, B1f[kk][nt], acc[nt]);
    }
#pragma unroll
    for (int nt = 0; nt < 4; ++nt)
#pragma unroll
      for (int r = 0; r < 4; ++r) {
        float h = fmaxf(acc[nt][r] + bias1[nt], 0.f);
        h1s[wave][lg * 4 + r][nt * 16 + l15] = (f16)h;
      }

    f32x4 out[NT2];
#pragma unroll
    for (int nt = 0; nt < NT2; ++nt) { out[nt][0] = 0.f; out[nt][1] = 0.f; out[nt][2] = 0.f; out[nt][3] = 0.f; }
#pragma unroll
    for (int kk = 0; kk < 2; ++kk) {
      f16x8 hf = *(const f16x8*)&h1s[wave][l15][kk * 32 + lg * 8];
#pragma unroll
      for (int nt = 0; nt < NT2; ++nt) out[nt] = mfma16(hf, B2f[kk][nt], out[nt]);
    }
#pragma unroll
    for (int r = 0; r < 4; ++r) {
      const int row = n0 + lg * 4 + r;
#pragma unroll
      for (int nt = 0; nt < NT2; ++nt) {
        const int col = nt * 16 + l15;
        float v = out[nt][r] + bias2[nt];
        if (STAGE == 0) {
          xl[(size_t)row * 64 + col] = v;
          xho[(size_t)row * 64 + col] = (f16)v;
        } else if (STAGE == 1) {
          float nv = xl[(size_t)row * 64 + col] + v;
          xl[(size_t)row * 64 + col] = nv;
          xho[(size_t)row * 64 + col] = (f16)nv;
        } else {
          if (col < OUTW) outp[(size_t)row * OUTW + col] = v;
        }
      }
    }
  }
}

// ---------------- launch ----------------

extern "C" void kernel_launch(void* const* d_in, const int* in_sizes, int n_in,
                              void* d_out, int out_size, void* d_ws, size_t ws_size,
                              hipStream_t stream) {
  const float* x  = (const float*)d_in[0];
  const int* ei   = (const int*)d_in[1];
  const float* ea = (const float*)d_in[2];
  const float* enc_e_b1 = (const float*)d_in[4];
  const float* enc_e_b2 = (const float*)d_in[6];
  const float* enc_n_b1 = (const float*)d_in[8];
  const float* enc_n_b2 = (const float*)d_in[10];
  const float* proc_e_b1 = (const float*)d_in[12];
  const float* proc_e_b2 = (const float*)d_in[14];
  const float* proc_n_b1 = (const float*)d_in[16];
  const float* proc_n_b2 = (const float*)d_in[18];
  const float* dec_e_b1 = (const float*)d_in[20];
  const float* dec_e_b2 = (const float*)d_in[22];
  const float* dec_n_b1 = (const float*)d_in[24];
  const float* dec_n_b2 = (const float*)d_in[26];

  const int* src = ei;
  const int* dst = ei + NE;

  // workspace layout (~167 MB total; R2 proved >= 263 MB available)
  char* p = (char*)d_ws;
  f16* el    = (f16*)p;   p += (size_t)NE * 64 * 2;   // 102.4 MB
  f16* Aenc  = (f16*)p;   p += (size_t)NE * 16 * 2;   // 25.6 MB
  float* xl  = (float*)p; p += (size_t)NN * 64 * 4;   // 12.8 MB
  f16* xh    = (f16*)p;   p += (size_t)NN * 64 * 2;   // 6.4 MB
  float* agg = (float*)p; p += (size_t)NN * 64 * 4;   // 12.8 MB f32 atomic accumulator
  int* cnt   = (int*)p;   p += (size_t)NN * 4;
  int* off   = (int*)p;   p += (size_t)(NN + 1) * 4;
  int* cur   = (int*)p;   p += (size_t)NN * 4;
  float* inv = (float*)p; p += (size_t)NN * 4;
  int* psrc  = (int*)p;   p += (size_t)NE * 4;
  int* pdst  = (int*)p;   p += (size_t)NE * 4;
  f16* wb    = (f16*)p;   p += 70656 * 2;
  f16* W1T_ence = wb + 0;
  f16* W2T_ence = wb + 2048;
  f16* W1T_encn = wb + 6144;
  f16* W2T_encn = wb + 12288;
  f16* W1T_proce = wb + 16384;
  f16* W2T_proce = wb + 28672;
  f16* W1T_procn = wb + 32768;
  f16* W2T_procn = wb + 40960;
  f16* W1T_dece = wb + 45056;
  f16* W2T_dece = wb + 57344;
  f16* W1T_decn = wb + 61440;
  f16* W2T_decn = wb + 69632;

  hipMemsetAsync(cnt, 0, (size_t)NN * 4, stream);
  hipMemsetAsync(wb, 0, 70656 * 2, stream);

  count_kernel<<<(NE + 255) / 256, 256, 0, stream>>>(dst, cnt);
  scan_kernel<<<1, 1024, 0, stream>>>(cnt, off, cur, inv);
  scatter_pack<<<(NE + 255) / 256, 256, 0, stream>>>(x, ea, src, dst, cur, psrc, pdst, Aenc);

  PrepPtrs P;
  P.W[0]  = (const float*)d_in[3];   // enc_e_w1
  P.W[1]  = (const float*)d_in[5];   // enc_e_w2
  P.W[2]  = (const float*)d_in[7];   // enc_n_w1 (raw part)
  P.W[3]  = (const float*)d_in[7];   // enc_n_w1 (agg part)
  P.W[4]  = (const float*)d_in[9];   // enc_n_w2
  P.W[5]  = (const float*)d_in[11];  // proc_e_w1
  P.W[6]  = (const float*)d_in[13];  // proc_e_w2
  P.W[7]  = (const float*)d_in[15];  // proc_n_w1
  P.W[8]  = (const float*)d_in[17];  // proc_n_w2
  P.W[9]  = (const float*)d_in[19];  // dec_e_w1
  P.W[10] = (const float*)d_in[21];  // dec_e_w2
  P.W[11] = (const float*)d_in[23];  // dec_n_w1
  P.W[12] = (const float*)d_in[25];  // dec_n_w2
  prep_all<<<13, 256, 0, stream>>>(P, wb);

  const int EDGE_BLK = 2048;  // strided mapping, 8192 waves
  const size_t AGG_BYTES = (size_t)NN * 64 * 4;

  // ---- encoder ----
  hipMemsetAsync(agg, 0, AGG_BYTES, stream);
  edge_mlp_kernel<0, 1><<<EDGE_BLK, 256, 0, stream>>>(Aenc, xh, el, el, psrc, pdst,
                                                      W1T_ence, W2T_ence, enc_e_b1, enc_e_b2, agg);
  node_mlp_kernel<0, 3, 4, 64><<<256, 256, 0, stream>>>(x, xh, agg, inv, W1T_encn, W2T_encn,
                                                        enc_n_b1, enc_n_b2, xl, xh, (float*)d_out);
  // ---- 2 processor rounds (shared weights, residuals) ----
  for (int r = 0; r < 2; ++r) {
    hipMemsetAsync(agg, 0, AGG_BYTES, stream);
    edge_mlp_kernel<1, 6><<<EDGE_BLK, 256, 0, stream>>>(Aenc, xh, el, el, psrc, pdst,
                                                        W1T_proce, W2T_proce, proc_e_b1, proc_e_b2, agg);
    node_mlp_kernel<1, 4, 4, 64><<<256, 256, 0, stream>>>(x, xh, agg, inv, W1T_procn, W2T_procn,
                                                          proc_n_b1, proc_n_b2, xl, xh, (float*)d_out);
  }
  // ---- decoder (no el write; agg of ed only) ----
  hipMemsetAsync(agg, 0, AGG_BYTES, stream);
  edge_mlp_kernel<2, 6><<<EDGE_BLK, 256, 0, stream>>>(Aenc, xh, el, el, psrc, pdst,
                                                      W1T_dece, W2T_dece, dec_e_b1, dec_e_b2, agg);
  node_mlp_kernel<2, 4, 1, 7><<<256, 256, 0, stream>>>(x, xh, agg, inv, W1T_decn, W2T_decn,
                                                       dec_n_b1, dec_n_b2, xl, xh, (float*)d_out);
}

// Round 7
// 748.160 us; speedup vs baseline: 1.4389x; 1.3656x over previous
//
#include <hip/hip_runtime.h>

#define NN 50000
#define NE 800000

typedef _Float16 f16;
typedef _Float16 f16x8 __attribute__((ext_vector_type(8)));
typedef float f32x4 __attribute__((ext_vector_type(4)));

__device__ __forceinline__ f16x8 fzero8() {
  f16x8 v;
#pragma unroll
  for (int i = 0; i < 8; ++i) v[i] = (f16)0.f;
  return v;
}

__device__ __forceinline__ f32x4 mfma16(f16x8 a, f16x8 b, f32x4 c) {
  return __builtin_amdgcn_mfma_f32_16x16x32_f16(a, b, c, 0, 0, 0);
}

// ---------------- prep kernels ----------------

__global__ void count_kernel(const int* __restrict__ dst, int* __restrict__ cnt) {
  int e = blockIdx.x * 256 + threadIdx.x;
  if (e < NE) atomicAdd(&cnt[dst[e]], 1);
}

// single-block exclusive scan over cnt -> off/cur, plus inv = 1/max(cnt,1)
__global__ void scan_kernel(const int* __restrict__ cnt, int* __restrict__ off,
                            int* __restrict__ cur, float* __restrict__ inv) {
  __shared__ int part[1024];
  const int t = threadIdx.x;
  const int CH = (NN + 1023) / 1024;
  const int i0 = t * CH, i1 = (i0 + CH < NN) ? i0 + CH : NN;
  int s = 0;
  for (int i = i0; i < i1; ++i) s += cnt[i];
  part[t] = s;
  __syncthreads();
  for (int d = 1; d < 1024; d <<= 1) {
    int v = (t >= d) ? part[t - d] : 0;
    __syncthreads();
    part[t] += v;
    __syncthreads();
  }
  int base = (t > 0) ? part[t - 1] : 0;
  for (int i = i0; i < i1; ++i) {
    off[i] = base;
    cur[i] = base;
    inv[i] = 1.0f / fmaxf((float)cnt[i], 1.0f);
    base += cnt[i];
  }
  if (t == 1023) off[NN] = NE;
}

// scatter edges into dst-sorted order; also build packed encoder rows
__global__ void scatter_pack(const float* __restrict__ x, const float* __restrict__ ea,
                             const int* __restrict__ src, const int* __restrict__ dst,
                             int* __restrict__ cur, int* __restrict__ psrc,
                             int* __restrict__ pdst, f16* __restrict__ A) {
  int e = blockIdx.x * 256 + threadIdx.x;
  if (e >= NE) return;
  int s = src[e], d = dst[e];
  int pos = atomicAdd(&cur[d], 1);
  psrc[pos] = s;
  pdst[pos] = d;
  f16 row[16];
#pragma unroll
  for (int i = 0; i < 5; ++i) { row[i] = (f16)x[s * 5 + i]; row[5 + i] = (f16)x[d * 5 + i]; }
#pragma unroll
  for (int i = 0; i < 4; ++i) row[10 + i] = (f16)ea[e * 4 + i];
  row[14] = (f16)0.f; row[15] = (f16)0.f;
  *(f16x8*)(A + (size_t)pos * 16) = *(f16x8*)row;
  *(f16x8*)(A + (size_t)pos * 16 + 8) = *(f16x8*)(row + 8);
}

// all 13 weight transposes in one launch; block b handles matrix b
struct PrepPtrs { const float* W[13]; };
__global__ void prep_all(PrepPtrs P, f16* __restrict__ out) {
  const int Nw[13]   = {64,64,64,64,64,64,64,64,64,64,64,64,7};
  const int Kd[13]   = {32,64,96,96,64,192,64,128,64,192,64,128,64};
  const int ks[13]   = {0,0,0,5,0,0,0,0,0,0,0,0,0};
  const int kd[13]   = {0,0,0,32,0,0,0,0,0,0,0,0,0};
  const int klen[13] = {14,64,5,64,64,192,64,128,64,192,64,128,64};
  const int nc[13]   = {64,64,64,64,64,64,64,64,64,64,64,64,7};
  const int ofs[13]  = {0,2048,6144,6144,12288,16384,28672,32768,40960,45056,57344,61440,69632};
  const int m = blockIdx.x;
  const float* W = P.W[m];
  const int tot = klen[m] * nc[m];
  for (int idx = threadIdx.x; idx < tot; idx += 256) {
    int kk = idx / nc[m], n = idx % nc[m];
    out[ofs[m] + n * Kd[m] + kd[m] + kk] = (f16)W[(ks[m] + kk) * Nw[m] + n];
  }
}

// ---------------- edge MLP (LDS-staged weights + A-side double buffer) ----------------
// STAGE: 0=encoder (A from packed Aenc, write el, agg += el)
//        1=processor (A=[xh[src]|xh[dst]|el], el += ed in place, agg += ed)
//        2=decoder   (A same as proc, NO el write, agg += ed)
template <int STAGE, int KT1>
__global__ __launch_bounds__(256, 3)
void edge_mlp_kernel(const f16* __restrict__ Aenc,
                     const f16* __restrict__ xh,
                     const f16* elr, f16* elw,
                     const int* __restrict__ psrc,
                     const int* __restrict__ pdst,
                     const f16* __restrict__ B1,
                     const f16* __restrict__ B2,
                     const float* __restrict__ b1,
                     const float* __restrict__ b2,
                     float* __restrict__ agg) {
  constexpr int K1 = KT1 * 32;
  constexpr int NF1 = KT1 * 4;              // L1 fragment count
  constexpr int NA = (STAGE == 0) ? 1 : 6;  // A fragments per group
  __shared__ __align__(16) f16 h1s[4][16][72];
  __shared__ __align__(16) f16 B1s[NF1 * 64 * 8];
  __shared__ __align__(16) f16 B2s[8 * 64 * 8];

  const int wave = threadIdx.x >> 6;
  const int lane = threadIdx.x & 63;
  const int l15 = lane & 15, lg = lane >> 4;
  const int nwaves = gridDim.x * 4;
  const int wid = blockIdx.x * 4 + wave;     // wid < 8192 << NG, always active
  const int NG = NE / 16;

  // ---- stage weight fragments into LDS (fragment-major, conflict-free reads) ----
  for (int f = wave; f < NF1; f += 4) {
    const int kk = f >> 2, nt = f & 3;
    *(f16x8*)&B1s[(f * 64 + lane) * 8] =
        *(const f16x8*)(B1 + (nt * 16 + l15) * K1 + kk * 32 + lg * 8);
  }
  for (int f = wave; f < 8; f += 4) {
    const int kk = f >> 2, nt = f & 3;
    *(f16x8*)&B2s[(f * 64 + lane) * 8] =
        *(const f16x8*)(B2 + (nt * 16 + l15) * 64 + kk * 32 + lg * 8);
  }
  float bias1[4], bias2[4];
#pragma unroll
  for (int nt = 0; nt < 4; ++nt) { bias1[nt] = b1[nt * 16 + l15]; bias2[nt] = b2[nt * 16 + l15]; }
  __syncthreads();

  // ---- A-fragment loader ----
  auto loadA = [&](int g, int s, int d, f16x8* a) {
    const int erA = g * 16 + l15;
    if (STAGE == 0) {
      a[0] = fzero8();
      if (lg < 2) a[0] = *(const f16x8*)(Aenc + (size_t)erA * 16 + lg * 8);
    } else {
      a[0] = *(const f16x8*)(xh + (size_t)s * 64 + lg * 8);
      a[1] = *(const f16x8*)(xh + (size_t)s * 64 + 32 + lg * 8);
      a[2] = *(const f16x8*)(xh + (size_t)d * 64 + lg * 8);
      a[3] = *(const f16x8*)(xh + (size_t)d * 64 + 32 + lg * 8);
      a[4] = *(const f16x8*)(elr + (size_t)erA * 64 + lg * 8);
      a[5] = *(const f16x8*)(elr + (size_t)erA * 64 + 32 + lg * 8);
    }
  };

  // ---- software pipeline: idx 2-deep, A-frags 1-deep ----
  int sA = 0, dA = 0, sB = 0, dB = 0;
  dA = pdst[wid * 16 + l15];
  if (STAGE != 0) sA = psrc[wid * 16 + l15];
  f16x8 aCur[NA], aNxt[NA];
  loadA(wid, sA, dA, aCur);
  {
    const int g2 = wid + nwaves;
    if (g2 < NG) {
      dB = pdst[g2 * 16 + l15];
      if (STAGE != 0) sB = psrc[g2 * 16 + l15];
    }
  }

  for (int g = wid; g < NG; g += nwaves) {
    const int gN = g + nwaves;
    if (gN < NG) loadA(gN, sB, dB, aNxt);          // prefetch next group's A
    int sC = 0, dC = 0;
    const int g3 = g + 2 * nwaves;
    if (g3 < NG) {                                  // prefetch idx 2 ahead
      dC = pdst[g3 * 16 + l15];
      if (STAGE != 0) sC = psrc[g3 * 16 + l15];
    }

    // ---- layer 1: MFMA with LDS B-frags ----
    f32x4 acc[4];
#pragma unroll
    for (int nt = 0; nt < 4; ++nt) { acc[nt][0] = 0.f; acc[nt][1] = 0.f; acc[nt][2] = 0.f; acc[nt][3] = 0.f; }
#pragma unroll
    for (int kk = 0; kk < KT1; ++kk) {
      const f16x8 a = aCur[(STAGE == 0) ? 0 : kk];
#pragma unroll
      for (int nt = 0; nt < 4; ++nt) {
        const f16x8 b = *(const f16x8*)&B1s[((kk * 4 + nt) * 64 + lane) * 8];
        acc[nt] = mfma16(a, b, acc[nt]);
      }
    }
    // bias + relu, stage h1 to LDS (C-layout -> A-layout); per-wave slice
#pragma unroll
    for (int nt = 0; nt < 4; ++nt)
#pragma unroll
      for (int r = 0; r < 4; ++r) {
        float h = fmaxf(acc[nt][r] + bias1[nt], 0.f);
        h1s[wave][lg * 4 + r][nt * 16 + l15] = (f16)h;
      }

    // ---- layer 2 ----
    f32x4 out[4];
#pragma unroll
    for (int nt = 0; nt < 4; ++nt) { out[nt][0] = 0.f; out[nt][1] = 0.f; out[nt][2] = 0.f; out[nt][3] = 0.f; }
#pragma unroll
    for (int kk = 0; kk < 2; ++kk) {
      const f16x8 hf = *(const f16x8*)&h1s[wave][l15][kk * 32 + lg * 8];
#pragma unroll
      for (int nt = 0; nt < 4; ++nt) {
        const f16x8 b = *(const f16x8*)&B2s[((kk * 4 + nt) * 64 + lane) * 8];
        out[nt] = mfma16(hf, b, out[nt]);
      }
    }

    // stage ed (bias added) back to LDS rows
#pragma unroll
    for (int nt = 0; nt < 4; ++nt)
#pragma unroll
      for (int r = 0; r < 4; ++r)
        h1s[wave][lg * 4 + r][nt * 16 + l15] = (f16)(out[nt][r] + bias2[nt]);

    // global el write (encoder: fresh; proc: in-place residual; decoder: none)
    const int erA = g * 16 + l15;
    if (STAGE != 2) {
      f16x8 v0 = *(const f16x8*)&h1s[wave][l15][lg * 8];
      f16x8 v1 = *(const f16x8*)&h1s[wave][l15][32 + lg * 8];
      f16* p0 = elw + (size_t)erA * 64 + lg * 8;
      if (STAGE == 1) {
        f16x8 n0, n1;
#pragma unroll
        for (int j = 0; j < 8; ++j) {
          n0[j] = (f16)((float)aCur[4][j] + (float)v0[j]);
          n1[j] = (f16)((float)aCur[5][j] + (float)v1[j]);
        }
        *(f16x8*)p0 = n0;
        *(f16x8*)(p0 + 32) = n1;
      } else {
        *(f16x8*)p0 = v0;
        *(f16x8*)(p0 + 32) = v1;
      }
    }

    // fused segmented reduction: lane = column, walk 16 sorted rows,
    // one coalesced 64-lane atomicAdd per dst segment (dst wave-uniform).
    {
      float racc = 0.f;
      int dprev = __shfl(dA, 0);
#pragma unroll
      for (int row = 0; row < 16; ++row) {
        const int dn = __shfl(dA, row);
        const float v = (float)h1s[wave][row][lane];
        if (dn != dprev) {
          atomicAdd(agg + (size_t)dprev * 64 + lane, racc);
          racc = 0.f;
          dprev = dn;
        }
        racc += v;
      }
      atomicAdd(agg + (size_t)dprev * 64 + lane, racc);
    }

    // rotate pipeline
#pragma unroll
    for (int i = 0; i < NA; ++i) aCur[i] = aNxt[i];
    sA = sB; dA = dB; sB = sC; dB = dC;
  }
}

// ---------------- node MLP (LDS-staged weights, fused mean-finish) ----------------
// STAGE: 0=encoder (A=[x_raw(5,pad32)|agg*inv], out: xl=v, xh=f16(v))
//        1=processor (A=[xh|agg*inv], xl += v, xh mirror)
//        2=decoder   (A=[xh|agg*inv], write d_out[N][7])
template <int STAGE, int KT1, int NT2, int OUTW>
__global__ __launch_bounds__(256, 4)
void node_mlp_kernel(const float* __restrict__ xraw,
                     const f16* xh,
                     const float* __restrict__ agg,
                     const float* __restrict__ inv,
                     const f16* __restrict__ B1,
                     const f16* __restrict__ B2,
                     const float* __restrict__ b1,
                     const float* __restrict__ b2,
                     float* __restrict__ xl,
                     f16* xho,
                     float* __restrict__ outp) {
  constexpr int K1 = KT1 * 32;
  constexpr int NF1 = KT1 * 4;
  constexpr int NF2 = 2 * NT2;
  __shared__ __align__(16) f16 h1s[4][16][72];
  __shared__ __align__(16) f16 B1s[NF1 * 64 * 8];
  __shared__ __align__(16) f16 B2s[NF2 * 64 * 8];
  const int wave = threadIdx.x >> 6;
  const int lane = threadIdx.x & 63;
  const int l15 = lane & 15, lg = lane >> 4;
  const int nwaves = gridDim.x * 4;
  const int wid = blockIdx.x * 4 + wave;
  const int NG = NN / 16;

  for (int f = wave; f < NF1; f += 4) {
    const int kk = f >> 2, nt = f & 3;
    *(f16x8*)&B1s[(f * 64 + lane) * 8] =
        *(const f16x8*)(B1 + (nt * 16 + l15) * K1 + kk * 32 + lg * 8);
  }
  for (int f = wave; f < NF2; f += 4) {
    const int kk = f / NT2, nt = f % NT2;
    *(f16x8*)&B2s[(f * 64 + lane) * 8] =
        *(const f16x8*)(B2 + (nt * 16 + l15) * 64 + kk * 32 + lg * 8);
  }
  float bias1[4], bias2[NT2];
#pragma unroll
  for (int nt = 0; nt < 4; ++nt) bias1[nt] = b1[nt * 16 + l15];
#pragma unroll
  for (int nt = 0; nt < NT2; ++nt) bias2[nt] = (nt * 16 + l15 < OUTW) ? b2[nt * 16 + l15] : 0.f;
  __syncthreads();

  for (int g = wid; g < NG; g += nwaves) {
    const int n0 = g * 16;
    const int rA = n0 + l15;
    const float iv = inv[rA];

    f32x4 acc[4];
#pragma unroll
    for (int nt = 0; nt < 4; ++nt) { acc[nt][0] = 0.f; acc[nt][1] = 0.f; acc[nt][2] = 0.f; acc[nt][3] = 0.f; }

#pragma unroll
    for (int kk = 0; kk < KT1; ++kk) {
      f16x8 a;
      if (STAGE == 0 && kk == 0) {
        a = fzero8();
        if (lg == 0) {
#pragma unroll
          for (int j = 0; j < 5; ++j) a[j] = (f16)xraw[(size_t)rA * 5 + j];
        }
      } else if (STAGE != 0 && kk < 2) {
        a = *(const f16x8*)(xh + (size_t)rA * 64 + kk * 32 + lg * 8);
      } else {
        const int ko = (STAGE == 0) ? (kk - 1) : (kk - 2);
        const float* ap = agg + (size_t)rA * 64 + ko * 32 + lg * 8;
        f32x4 a0 = *(const f32x4*)ap;
        f32x4 a1 = *(const f32x4*)(ap + 4);
#pragma unroll
        for (int j = 0; j < 4; ++j) { a[j] = (f16)(a0[j] * iv); a[4 + j] = (f16)(a1[j] * iv); }
      }
#pragma unroll
      for (int nt = 0; nt < 4; ++nt) {
        const f16x8 b = *(const f16x8*)&B1s[((kk * 4 + nt) * 64 + lane) * 8];
        acc[nt] = mfma16(a, b, acc[nt]);
      }
    }
#pragma unroll
    for (int nt = 0; nt < 4; ++nt)
#pragma unroll
      for (int r = 0; r < 4; ++r) {
        float h = fmaxf(acc[nt][r] + bias1[nt], 0.f);
        h1s[wave][lg * 4 + r][nt * 16 + l15] = (f16)h;
      }

    f32x4 out[NT2];
#pragma unroll
    for (int nt = 0; nt < NT2; ++nt) { out[nt][0] = 0.f; out[nt][1] = 0.f; out[nt][2] = 0.f; out[nt][3] = 0.f; }
#pragma unroll
    for (int kk = 0; kk < 2; ++kk) {
      const f16x8 hf = *(const f16x8*)&h1s[wave][l15][kk * 32 + lg * 8];
#pragma unroll
      for (int nt = 0; nt < NT2; ++nt) {
        const f16x8 b = *(const f16x8*)&B2s[((kk * NT2 + nt) * 64 + lane) * 8];
        out[nt] = mfma16(hf, b, out[nt]);
      }
    }
#pragma unroll
    for (int r = 0; r < 4; ++r) {
      const int row = n0 + lg * 4 + r;
#pragma unroll
      for (int nt = 0; nt < NT2; ++nt) {
        const int col = nt * 16 + l15;
        float v = out[nt][r] + bias2[nt];
        if (STAGE == 0) {
          xl[(size_t)row * 64 + col] = v;
          xho[(size_t)row * 64 + col] = (f16)v;
        } else if (STAGE == 1) {
          float nv = xl[(size_t)row * 64 + col] + v;
          xl[(size_t)row * 64 + col] = nv;
          xho[(size_t)row * 64 + col] = (f16)nv;
        } else {
          if (col < OUTW) outp[(size_t)row * OUTW + col] = v;
        }
      }
    }
  }
}

// ---------------- launch ----------------

extern "C" void kernel_launch(void* const* d_in, const int* in_sizes, int n_in,
                              void* d_out, int out_size, void* d_ws, size_t ws_size,
                              hipStream_t stream) {
  const float* x  = (const float*)d_in[0];
  const int* ei   = (const int*)d_in[1];
  const float* ea = (const float*)d_in[2];
  const float* enc_e_b1 = (const float*)d_in[4];
  const float* enc_e_b2 = (const float*)d_in[6];
  const float* enc_n_b1 = (const float*)d_in[8];
  const float* enc_n_b2 = (const float*)d_in[10];
  const float* proc_e_b1 = (const float*)d_in[12];
  const float* proc_e_b2 = (const float*)d_in[14];
  const float* proc_n_b1 = (const float*)d_in[16];
  const float* proc_n_b2 = (const float*)d_in[18];
  const float* dec_e_b1 = (const float*)d_in[20];
  const float* dec_e_b2 = (const float*)d_in[22];
  const float* dec_n_b1 = (const float*)d_in[24];
  const float* dec_n_b2 = (const float*)d_in[26];

  const int* src = ei;
  const int* dst = ei + NE;

  // workspace layout (~167 MB total; R2 proved >= 263 MB available)
  char* p = (char*)d_ws;
  f16* el    = (f16*)p;   p += (size_t)NE * 64 * 2;   // 102.4 MB
  f16* Aenc  = (f16*)p;   p += (size_t)NE * 16 * 2;   // 25.6 MB
  float* xl  = (float*)p; p += (size_t)NN * 64 * 4;   // 12.8 MB
  f16* xh    = (f16*)p;   p += (size_t)NN * 64 * 2;   // 6.4 MB
  float* agg = (float*)p; p += (size_t)NN * 64 * 4;   // 12.8 MB f32 atomic accumulator
  int* cnt   = (int*)p;   p += (size_t)NN * 4;
  int* off   = (int*)p;   p += (size_t)(NN + 1) * 4;
  int* cur   = (int*)p;   p += (size_t)NN * 4;
  float* inv = (float*)p; p += (size_t)NN * 4;
  int* psrc  = (int*)p;   p += (size_t)NE * 4;
  int* pdst  = (int*)p;   p += (size_t)NE * 4;
  f16* wb    = (f16*)p;   p += 70656 * 2;
  f16* W1T_ence = wb + 0;
  f16* W2T_ence = wb + 2048;
  f16* W1T_encn = wb + 6144;
  f16* W2T_encn = wb + 12288;
  f16* W1T_proce = wb + 16384;
  f16* W2T_proce = wb + 28672;
  f16* W1T_procn = wb + 32768;
  f16* W2T_procn = wb + 40960;
  f16* W1T_dece = wb + 45056;
  f16* W2T_dece = wb + 57344;
  f16* W1T_decn = wb + 61440;
  f16* W2T_decn = wb + 69632;

  hipMemsetAsync(cnt, 0, (size_t)NN * 4, stream);
  hipMemsetAsync(wb, 0, 70656 * 2, stream);

  count_kernel<<<(NE + 255) / 256, 256, 0, stream>>>(dst, cnt);
  scan_kernel<<<1, 1024, 0, stream>>>(cnt, off, cur, inv);
  scatter_pack<<<(NE + 255) / 256, 256, 0, stream>>>(x, ea, src, dst, cur, psrc, pdst, Aenc);

  PrepPtrs P;
  P.W[0]  = (const float*)d_in[3];   // enc_e_w1
  P.W[1]  = (const float*)d_in[5];   // enc_e_w2
  P.W[2]  = (const float*)d_in[7];   // enc_n_w1 (raw part)
  P.W[3]  = (const float*)d_in[7];   // enc_n_w1 (agg part)
  P.W[4]  = (const float*)d_in[9];   // enc_n_w2
  P.W[5]  = (const float*)d_in[11];  // proc_e_w1
  P.W[6]  = (const float*)d_in[13];  // proc_e_w2
  P.W[7]  = (const float*)d_in[15];  // proc_n_w1
  P.W[8]  = (const float*)d_in[17];  // proc_n_w2
  P.W[9]  = (const float*)d_in[19];  // dec_e_w1
  P.W[10] = (const float*)d_in[21];  // dec_e_w2
  P.W[11] = (const float*)d_in[23];  // dec_n_w1
  P.W[12] = (const float*)d_in[25];  // dec_n_w2
  prep_all<<<13, 256, 0, stream>>>(P, wb);

  const int EDGE_BLK = 2048;  // strided mapping, 8192 waves
  const size_t AGG_BYTES = (size_t)NN * 64 * 4;

  // ---- encoder ----
  hipMemsetAsync(agg, 0, AGG_BYTES, stream);
  edge_mlp_kernel<0, 1><<<EDGE_BLK, 256, 0, stream>>>(Aenc, xh, el, el, psrc, pdst,
                                                      W1T_ence, W2T_ence, enc_e_b1, enc_e_b2, agg);
  node_mlp_kernel<0, 3, 4, 64><<<256, 256, 0, stream>>>(x, xh, agg, inv, W1T_encn, W2T_encn,
                                                        enc_n_b1, enc_n_b2, xl, xh, (float*)d_out);
  // ---- 2 processor rounds (shared weights, residuals) ----
  for (int r = 0; r < 2; ++r) {
    hipMemsetAsync(agg, 0, AGG_BYTES, stream);
    edge_mlp_kernel<1, 6><<<EDGE_BLK, 256, 0, stream>>>(Aenc, xh, el, el, psrc, pdst,
                                                        W1T_proce, W2T_proce, proc_e_b1, proc_e_b2, agg);
    node_mlp_kernel<1, 4, 4, 64><<<256, 256, 0, stream>>>(x, xh, agg, inv, W1T_procn, W2T_procn,
                                                          proc_n_b1, proc_n_b2, xl, xh, (float*)d_out);
  }
  // ---- decoder (no el write; agg of ed only) ----
  hipMemsetAsync(agg, 0, AGG_BYTES, stream);
  edge_mlp_kernel<2, 6><<<EDGE_BLK, 256, 0, stream>>>(Aenc, xh, el, el, psrc, pdst,
                                                      W1T_dece, W2T_dece, dec_e_b1, dec_e_b2, agg);
  node_mlp_kernel<2, 4, 1, 7><<<256, 256, 0, stream>>>(x, xh, agg, inv, W1T_decn, W2T_decn,
                                                       dec_n_b1, dec_n_b2, xl, xh, (float*)d_out);
}